// Round 1
// baseline (919.090 us; speedup 1.0000x reference)
//
#include <hip/hip_runtime.h>
#include <hip/hip_bf16.h>

typedef float f4 __attribute__((ext_vector_type(4)));

#define EMB 128
#define HID 512
#define HEADS 8
#define DH 16

__device__ __forceinline__ float bfbits2f(unsigned int lo16) {
    unsigned int u = lo16 << 16;
    return __builtin_bit_cast(float, u);
}

// ---------------------------------------------------------------------------
// Scatter: cnt[a] += 1, xsum[a,:] += x[b,:] for each edge (a,b).
// Thread per (edge, col). Within a wave: one edge, 64 consecutive cols ->
// coalesced x reads and consecutive-address atomics.
// ---------------------------------------------------------------------------
__global__ void scatter_kernel(const int* __restrict__ edge, const float* __restrict__ x,
                               float* __restrict__ xsum, float* __restrict__ cnt, int E) {
    size_t total = (size_t)E * EMB;
    size_t stride = (size_t)gridDim.x * blockDim.x;
    for (size_t idx = (size_t)blockIdx.x * blockDim.x + threadIdx.x; idx < total; idx += stride) {
        int e = (int)(idx >> 7);
        int d = (int)(idx & 127);
        int a = edge[e];
        int b = edge[E + e];
        float val = x[(size_t)b * EMB + d];
        unsafeAtomicAdd(&xsum[(size_t)a * EMB + d], val);
        if (d == 0) unsafeAtomicAdd(&cnt[a], 1.0f);
    }
}

// ---------------------------------------------------------------------------
// Generic GEMM: out[r, cb+c] = sum_k Xin[r,k] * W[k, cb+c] (+ fused epilogues)
// Block: 256 threads; per iter 32 rows x 128 cols; thread computes 4x4.
// W chunk [128][128] fp32 staged in LDS (64KB), X rows [32][128] (16KB).
// KT = total K (128 or 512, looped in chunks of 128).
// ---------------------------------------------------------------------------
template<int KT, bool SCALED_BIAS, bool IN_BF16, bool INSCALE, bool GELU_OUT, bool OUT_BF16, bool RESID>
__global__ __launch_bounds__(256, 2) void gemm_k(
    const void* __restrict__ Xv, const float* __restrict__ W, const float* __restrict__ bias,
    const float* __restrict__ rowscale,
    const float* __restrict__ in_scale, const float* __restrict__ in_shift,
    const float* __restrict__ resid, const float* __restrict__ r_scale, const float* __restrict__ r_shift,
    void* __restrict__ outv, int n, int OCtot)
{
    constexpr int KCH = KT / 128;
    __shared__ f4 Ws4[128 * 32];  // [k][c/4] : 64KB
    __shared__ f4 Xs4[32 * 32];   // [r][k/4] : 16KB

    const int tid = threadIdx.x;
    const int cq = tid & 31;   // col group: cols 4*cq..4*cq+3
    const int rq = tid >> 5;   // row group: rows 4*rq..4*rq+3
    const int cb = blockIdx.y * 128;
    const float* Xf = (const float*)Xv;
    const __hip_bfloat16* Xb = (const __hip_bfloat16*)Xv;

    auto stageW = [&](int kc) {
#pragma unroll
        for (int i = 0; i < 16; ++i) {
            int f = i * 256 + tid;
            int k = f >> 5, c4 = f & 31;
            Ws4[k * 32 + c4] = *(const f4*)(W + (size_t)(kc * 128 + k) * OCtot + cb + c4 * 4);
        }
    };
    auto stageX = [&](int R0, int kc) {
#pragma unroll
        for (int i = 0; i < 4; ++i) {
            int f = i * 256 + tid;
            int r = f >> 5, k4 = f & 31;
            int row = R0 + r;
            f4 vv = 0.f;
            if (row < n) {
                size_t base = (size_t)row * KT + kc * 128 + k4 * 4;
                if constexpr (IN_BF16) {
                    uint2 raw = *(const uint2*)(Xb + base);
                    vv[0] = bfbits2f(raw.x & 0xffffu);
                    vv[1] = bfbits2f(raw.x >> 16);
                    vv[2] = bfbits2f(raw.y & 0xffffu);
                    vv[3] = bfbits2f(raw.y >> 16);
                } else {
                    vv = *(const f4*)(Xf + base);
                }
                if constexpr (INSCALE) {
                    int kg = kc * 128 + k4 * 4;
#pragma unroll
                    for (int j = 0; j < 4; ++j) vv[j] = vv[j] * in_scale[kg + j] + in_shift[kg + j];
                }
            }
            Xs4[r * 32 + k4] = vv;
        }
    };

    if constexpr (KCH == 1) { stageW(0); }

    for (int R0 = blockIdx.x * 32; R0 < n; R0 += gridDim.x * 32) {
        f4 acc[4];
        acc[0] = 0.f; acc[1] = 0.f; acc[2] = 0.f; acc[3] = 0.f;

#pragma unroll
        for (int kc = 0; kc < KCH; ++kc) {
            if constexpr (KCH > 1) { __syncthreads(); stageW(kc); }
            stageX(R0, kc);
            __syncthreads();
#pragma unroll 4
            for (int k4 = 0; k4 < 32; ++k4) {
                f4 xa0 = Xs4[(rq * 4 + 0) * 32 + k4];
                f4 xa1 = Xs4[(rq * 4 + 1) * 32 + k4];
                f4 xa2 = Xs4[(rq * 4 + 2) * 32 + k4];
                f4 xa3 = Xs4[(rq * 4 + 3) * 32 + k4];
#pragma unroll
                for (int j = 0; j < 4; ++j) {
                    f4 w = Ws4[(k4 * 4 + j) * 32 + cq];
                    acc[0] += xa0[j] * w;
                    acc[1] += xa1[j] * w;
                    acc[2] += xa2[j] * w;
                    acc[3] += xa3[j] * w;
                }
            }
            if constexpr (KCH == 1) __syncthreads();
        }

        // epilogue
        int ccol = cb + cq * 4;
        f4 b4 = *(const f4*)(bias + ccol);
        f4 rsc = 0.f, rsh = 0.f;
        if constexpr (RESID) {
            if (r_scale) { rsc = *(const f4*)(r_scale + ccol); rsh = *(const f4*)(r_shift + ccol); }
        }
#pragma unroll
        for (int r = 0; r < 4; ++r) {
            int row = R0 + rq * 4 + r;
            if (row < n) {
                f4 val = acc[r];
                if constexpr (SCALED_BIAS) { float cv = rowscale[row]; val += b4 * cv; }
                else                        { val += b4; }
                if constexpr (RESID) {
                    f4 rv = *(const f4*)(resid + (size_t)row * EMB + ccol);
                    if (r_scale) rv = rv * rsc + rsh;
                    val += rv;
                }
                if constexpr (GELU_OUT) {
#pragma unroll
                    for (int j = 0; j < 4; ++j) {
                        float xg = val[j];
                        val[j] = 0.5f * xg * (1.0f + erff(xg * 0.70710678f));
                    }
                }
                if constexpr (OUT_BF16) {
                    __hip_bfloat16* ob = (__hip_bfloat16*)outv;
                    union { ushort4 u; __hip_bfloat16 h[4]; } pk;
#pragma unroll
                    for (int j = 0; j < 4; ++j) pk.h[j] = __float2bfloat16(val[j]);
                    *(ushort4*)(ob + (size_t)row * OCtot + ccol) = pk.u;
                } else {
                    *(f4*)((float*)outv + (size_t)row * OCtot + ccol) = val;
                }
            }
        }
    }
}

// ---------------------------------------------------------------------------
// Attention: one wave per node. lane = (h,g) in 8x8. S = (q_h . ksum_g)/max(cnt,1)
// softmax over g (8-lane shuffle groups), out[h,d] = sum_g P[h,g] * v[g,d].
// ---------------------------------------------------------------------------
__global__ void attn_kernel(const float* __restrict__ q, const float* __restrict__ ks,
                            const float* __restrict__ v, const float* __restrict__ cnt,
                            float* __restrict__ out, int n) {
    int wavesPerBlock = blockDim.x >> 6;
    int wid = blockIdx.x * wavesPerBlock + (threadIdx.x >> 6);
    int lane = threadIdx.x & 63;
    int totalWaves = gridDim.x * wavesPerBlock;
    int h = lane >> 3, g = lane & 7;
    for (int node = wid; node < n; node += totalWaves) {
        const f4* q4 = (const f4*)(q + (size_t)node * EMB + h * DH);
        const f4* k4 = (const f4*)(ks + (size_t)node * EMB + g * DH);
        float s = 0.f;
#pragma unroll
        for (int i = 0; i < 4; ++i) {
            f4 a = q4[i], b = k4[i];
            s += a[0] * b[0] + a[1] * b[1] + a[2] * b[2] + a[3] * b[3];
        }
        float c = cnt[node];
        s *= 1.0f / fmaxf(c, 1.0f);
        float m = s;
#pragma unroll
        for (int off = 1; off < 8; off <<= 1) m = fmaxf(m, __shfl_xor(m, off, 64));
        float e = __expf(s - m);
        float sum = e;
#pragma unroll
        for (int off = 1; off < 8; off <<= 1) sum += __shfl_xor(sum, off, 64);
        float p = e / sum;
        float o0 = 0.f, o1 = 0.f;
        int d0 = g * 2;
#pragma unroll
        for (int gg = 0; gg < 8; ++gg) {
            float pg = __shfl(p, h * 8 + gg, 64);
            const float2 vv = *(const float2*)(v + (size_t)node * EMB + gg * DH + d0);
            o0 += pg * vv.x; o1 += pg * vv.y;
        }
        *(float2*)(out + (size_t)node * EMB + h * DH + d0) = make_float2(o0, o1);
    }
}

// ---------------------------------------------------------------------------
// BatchNorm helpers
// ---------------------------------------------------------------------------
__global__ void bn_stats(const float* __restrict__ Y, float* __restrict__ sums, int n) {
    int c = threadIdx.x & 127;
    int rp = threadIdx.x >> 7;
    int r0 = blockIdx.x * 2 + rp;
    int stride = gridDim.x * 2;
    float s = 0.f, sq = 0.f;
    for (int r = r0; r < n; r += stride) {
        float vv = Y[(size_t)r * EMB + c];
        s += vv; sq += vv * vv;
    }
    unsafeAtomicAdd(&sums[c], s);
    unsafeAtomicAdd(&sums[128 + c], sq);
}

__global__ void bn_finalize(const float* __restrict__ sums, float* __restrict__ scsh,
                            const float* __restrict__ g, const float* __restrict__ be, int n) {
    int c = threadIdx.x;
    float invn = 1.0f / (float)n;
    float mean = sums[c] * invn;
    float var = sums[128 + c] * invn - mean * mean;
    var = fmaxf(var, 0.f);
    float sc = g[c] * rsqrtf(var + 1e-5f);
    scsh[c] = sc;
    scsh[128 + c] = be[c] - mean * sc;
}

__global__ void bn_apply(float* __restrict__ Y, const float* __restrict__ scsh, size_t total4) {
    size_t stride = (size_t)gridDim.x * blockDim.x;
    for (size_t i = (size_t)blockIdx.x * blockDim.x + threadIdx.x; i < total4; i += stride) {
        f4 vv = ((f4*)Y)[i];
        int c = (int)((i * 4) & 127);
#pragma unroll
        for (int j = 0; j < 4; ++j) vv[j] = vv[j] * scsh[c + j] + scsh[128 + c + j];
        ((f4*)Y)[i] = vv;
    }
}

// ---------------------------------------------------------------------------
extern "C" void kernel_launch(void* const* d_in, const int* in_sizes, int n_in,
                              void* d_out, int out_size, void* d_ws, size_t ws_size,
                              hipStream_t stream) {
    const float* x   = (const float*)d_in[0];
    const float* wq  = (const float*)d_in[1];
    const float* bq  = (const float*)d_in[2];
    const float* wk  = (const float*)d_in[3];
    const float* bk  = (const float*)d_in[4];
    const float* wv  = (const float*)d_in[5];
    const float* bv  = (const float*)d_in[6];
    const float* wo  = (const float*)d_in[7];
    const float* bo  = (const float*)d_in[8];
    const float* w1  = (const float*)d_in[9];
    const float* b1  = (const float*)d_in[10];
    const float* w2  = (const float*)d_in[11];
    const float* b2  = (const float*)d_in[12];
    const float* g1  = (const float*)d_in[13];
    const float* be1 = (const float*)d_in[14];
    const float* g2  = (const float*)d_in[15];
    const float* be2 = (const float*)d_in[16];
    const int* edge  = (const int*)d_in[17];

    int n = in_sizes[0] / EMB;      // 50000
    int E = in_sizes[17] / 2;       // 800000

    // workspace layout (fp32 elements)
    float* wsf  = (float*)d_ws;
    float* cnt  = wsf;                               // n (padded to 65536)
    float* xsum = wsf + 65536;                       // n*128
    float* q    = xsum + (size_t)n * EMB;            // n*128
    float* ksum = q    + (size_t)n * EMB;            // n*128
    float* v    = ksum + (size_t)n * EMB;            // n*128
    float* stats = v   + (size_t)n * EMB;            // 1024
    float* attno = xsum;                             // reuse (xsum dead after ksum GEMM)
    float* y1    = q;                                // reuse (q dead after attention)
    __hip_bfloat16* hbuf = (__hip_bfloat16*)ksum;    // n*512 bf16 spans ksum+v (both dead)
    float* y2 = (float*)d_out;                       // BN2 applied in place at the end

    hipMemsetAsync(cnt, 0, 65536 * sizeof(float), stream);
    hipMemsetAsync(xsum, 0, (size_t)n * EMB * sizeof(float), stream);
    hipMemsetAsync(stats, 0, 1024 * sizeof(float), stream);

    scatter_kernel<<<4096, 256, 0, stream>>>(edge, x, xsum, cnt, E);

    dim3 grd(512, 1);
    // q = x@wq + bq
    gemm_k<128, false, false, false, false, false, false><<<grd, 256, 0, stream>>>(
        x, wq, bq, nullptr, nullptr, nullptr, nullptr, nullptr, nullptr, q, n, EMB);
    // v = x@wv + bv
    gemm_k<128, false, false, false, false, false, false><<<grd, 256, 0, stream>>>(
        x, wv, bv, nullptr, nullptr, nullptr, nullptr, nullptr, nullptr, v, n, EMB);
    // ksum = xsum@wk + cnt*bk
    gemm_k<128, true, false, false, false, false, false><<<grd, 256, 0, stream>>>(
        xsum, wk, bk, cnt, nullptr, nullptr, nullptr, nullptr, nullptr, ksum, n, EMB);

    attn_kernel<<<512, 256, 0, stream>>>(q, ksum, v, cnt, attno, n);

    // y1 = attno@wo + bo + x
    gemm_k<128, false, false, false, false, false, true><<<grd, 256, 0, stream>>>(
        attno, wo, bo, nullptr, nullptr, nullptr, x, nullptr, nullptr, y1, n, EMB);

    bn_stats<<<512, 256, 0, stream>>>(y1, stats, n);
    bn_finalize<<<1, 128, 0, stream>>>(stats, stats + 256, g1, be1, n);

    // h = gelu(xn1@w1 + b1), bf16 out; xn1 applied on the fly from y1
    dim3 grd4(512, 4);
    gemm_k<128, false, false, true, true, true, false><<<grd4, 256, 0, stream>>>(
        y1, w1, b1, nullptr, stats + 256, stats + 384, nullptr, nullptr, nullptr, hbuf, n, HID);

    // y2 = h@w2 + b2 + xn1
    gemm_k<512, false, true, false, false, false, true><<<grd, 256, 0, stream>>>(
        hbuf, w2, b2, nullptr, nullptr, nullptr, y1, stats + 256, stats + 384, y2, n, EMB);

    bn_stats<<<512, 256, 0, stream>>>(y2, stats + 512, n);
    bn_finalize<<<1, 128, 0, stream>>>(stats + 512, stats + 768, g2, be2, n);
    bn_apply<<<512, 256, 0, stream>>>(y2, stats + 768, (size_t)n * EMB / 4);
}

// Round 2
// 824.049 us; speedup vs baseline: 1.1153x; 1.1153x over previous
//
#include <hip/hip_runtime.h>
#include <hip/hip_bf16.h>

typedef float f4 __attribute__((ext_vector_type(4)));

#define EMB 128
#define HID 512
#define HEADS 8
#define DH 16

__device__ __forceinline__ float bfbits2f(unsigned int lo16) {
    unsigned int u = lo16 << 16;
    return __builtin_bit_cast(float, u);
}

// ---------------------------------------------------------------------------
// Counting sort of edges by destination A.
// ---------------------------------------------------------------------------
__global__ void hist_kernel(const int* __restrict__ edge, unsigned* __restrict__ cnt, int E) {
    int stride = gridDim.x * blockDim.x;
    for (int e = blockIdx.x * blockDim.x + threadIdx.x; e < E; e += stride)
        atomicAdd(&cnt[edge[e]], 1u);
}

// single-block exclusive scan over n counts -> off (and a working copy offw),
// plus float copy of counts.
__global__ void scan_kernel(const unsigned* __restrict__ cnt, int* __restrict__ off,
                            int* __restrict__ offw, float* __restrict__ cntf, int n) {
    __shared__ int part[1024];
    int tid = threadIdx.x;
    int chunk = (n + 1023) / 1024;
    int base = tid * chunk;
    int s = 0;
    for (int i = 0; i < chunk; ++i) {
        int idx = base + i;
        if (idx < n) s += (int)cnt[idx];
    }
    part[tid] = s;
    __syncthreads();
    for (int d = 1; d < 1024; d <<= 1) {
        int t = (tid >= d) ? part[tid - d] : 0;
        __syncthreads();
        part[tid] += t;
        __syncthreads();
    }
    int run = part[tid] - s;  // exclusive prefix of this thread's chunk
    for (int i = 0; i < chunk; ++i) {
        int idx = base + i;
        if (idx < n) {
            int c = (int)cnt[idx];
            off[idx] = run;
            offw[idx] = run;
            cntf[idx] = (float)c;
            run += c;
        }
    }
}

__global__ void place_kernel(const int* __restrict__ edge, int* __restrict__ offw,
                             int* __restrict__ sortedB, int E) {
    int stride = gridDim.x * blockDim.x;
    for (int e = blockIdx.x * blockDim.x + threadIdx.x; e < E; e += stride) {
        int a = edge[e];
        int pos = atomicAdd(&offw[a], 1);
        sortedB[pos] = edge[E + e];
    }
}

// ---------------------------------------------------------------------------
// Gather: ksum[n,:] = sum over sorted neighbor list of k[b,:]
// One wave per node; lane covers cols lane and lane+64.
// ---------------------------------------------------------------------------
__global__ void gather_kernel(const float* __restrict__ k, const int* __restrict__ off,
                              const unsigned* __restrict__ cnt, const int* __restrict__ sortedB,
                              float* __restrict__ ksum, int n) {
    int wid = (int)((blockIdx.x * blockDim.x + threadIdx.x) >> 6);
    int lane = threadIdx.x & 63;
    int nw = (gridDim.x * blockDim.x) >> 6;
    for (int node = wid; node < n; node += nw) {
        int start = off[node];
        int deg = (int)cnt[node];
        float a0 = 0.f, a1 = 0.f;
        int j = 0;
        for (; j + 4 <= deg; j += 4) {
            int b0 = sortedB[start + j + 0];
            int b1 = sortedB[start + j + 1];
            int b2 = sortedB[start + j + 2];
            int b3 = sortedB[start + j + 3];
            float p0 = k[(size_t)b0 * EMB + lane];
            float p1 = k[(size_t)b1 * EMB + lane];
            float p2 = k[(size_t)b2 * EMB + lane];
            float p3 = k[(size_t)b3 * EMB + lane];
            float r0 = k[(size_t)b0 * EMB + 64 + lane];
            float r1 = k[(size_t)b1 * EMB + 64 + lane];
            float r2 = k[(size_t)b2 * EMB + 64 + lane];
            float r3 = k[(size_t)b3 * EMB + 64 + lane];
            a0 += (p0 + p1) + (p2 + p3);
            a1 += (r0 + r1) + (r2 + r3);
        }
        for (; j < deg; ++j) {
            int b = sortedB[start + j];
            a0 += k[(size_t)b * EMB + lane];
            a1 += k[(size_t)b * EMB + 64 + lane];
        }
        ksum[(size_t)node * EMB + lane] = a0;
        ksum[(size_t)node * EMB + 64 + lane] = a1;
    }
}

// ---------------------------------------------------------------------------
// Generic GEMM: out[r, cb+c] = sum_k Xin[r,k] * W[k, cb+c] (+ fused epilogues)
// Block: 256 threads; per iter 32 rows x 128 cols; thread computes 4x4.
// ---------------------------------------------------------------------------
template<int KT, bool SCALED_BIAS, bool IN_BF16, bool INSCALE, bool GELU_OUT, bool OUT_BF16, bool RESID>
__global__ __launch_bounds__(256, 2) void gemm_k(
    const void* __restrict__ Xv, const float* __restrict__ W, const float* __restrict__ bias,
    const float* __restrict__ rowscale,
    const float* __restrict__ in_scale, const float* __restrict__ in_shift,
    const float* __restrict__ resid, const float* __restrict__ r_scale, const float* __restrict__ r_shift,
    void* __restrict__ outv, int n, int OCtot)
{
    constexpr int KCH = KT / 128;
    __shared__ f4 Ws4[128 * 32];  // [k][c/4] : 64KB
    __shared__ f4 Xs4[32 * 32];   // [r][k/4] : 16KB

    const int tid = threadIdx.x;
    const int cq = tid & 31;   // col group: cols 4*cq..4*cq+3
    const int rq = tid >> 5;   // row group: rows 4*rq..4*rq+3
    const int cb = blockIdx.y * 128;
    const float* Xf = (const float*)Xv;
    const __hip_bfloat16* Xb = (const __hip_bfloat16*)Xv;

    auto stageW = [&](int kc) {
#pragma unroll
        for (int i = 0; i < 16; ++i) {
            int f = i * 256 + tid;
            int k = f >> 5, c4 = f & 31;
            Ws4[k * 32 + c4] = *(const f4*)(W + (size_t)(kc * 128 + k) * OCtot + cb + c4 * 4);
        }
    };
    auto stageX = [&](int R0, int kc) {
#pragma unroll
        for (int i = 0; i < 4; ++i) {
            int f = i * 256 + tid;
            int r = f >> 5, k4 = f & 31;
            int row = R0 + r;
            f4 vv = 0.f;
            if (row < n) {
                size_t base = (size_t)row * KT + kc * 128 + k4 * 4;
                if constexpr (IN_BF16) {
                    uint2 raw = *(const uint2*)(Xb + base);
                    vv[0] = bfbits2f(raw.x & 0xffffu);
                    vv[1] = bfbits2f(raw.x >> 16);
                    vv[2] = bfbits2f(raw.y & 0xffffu);
                    vv[3] = bfbits2f(raw.y >> 16);
                } else {
                    vv = *(const f4*)(Xf + base);
                }
                if constexpr (INSCALE) {
                    int kg = kc * 128 + k4 * 4;
#pragma unroll
                    for (int j = 0; j < 4; ++j) vv[j] = vv[j] * in_scale[kg + j] + in_shift[kg + j];
                }
            }
            Xs4[r * 32 + k4] = vv;
        }
    };

    if constexpr (KCH == 1) { stageW(0); }

    for (int R0 = blockIdx.x * 32; R0 < n; R0 += gridDim.x * 32) {
        f4 acc[4];
        acc[0] = 0.f; acc[1] = 0.f; acc[2] = 0.f; acc[3] = 0.f;

#pragma unroll
        for (int kc = 0; kc < KCH; ++kc) {
            if constexpr (KCH > 1) { __syncthreads(); stageW(kc); }
            stageX(R0, kc);
            __syncthreads();
#pragma unroll 4
            for (int k4 = 0; k4 < 32; ++k4) {
                f4 xa0 = Xs4[(rq * 4 + 0) * 32 + k4];
                f4 xa1 = Xs4[(rq * 4 + 1) * 32 + k4];
                f4 xa2 = Xs4[(rq * 4 + 2) * 32 + k4];
                f4 xa3 = Xs4[(rq * 4 + 3) * 32 + k4];
#pragma unroll
                for (int j = 0; j < 4; ++j) {
                    f4 w = Ws4[(k4 * 4 + j) * 32 + cq];
                    acc[0] += xa0[j] * w;
                    acc[1] += xa1[j] * w;
                    acc[2] += xa2[j] * w;
                    acc[3] += xa3[j] * w;
                }
            }
            if constexpr (KCH == 1) __syncthreads();
        }

        // epilogue
        int ccol = cb + cq * 4;
        f4 b4 = *(const f4*)(bias + ccol);
        f4 rsc = 0.f, rsh = 0.f;
        if constexpr (RESID) {
            if (r_scale) { rsc = *(const f4*)(r_scale + ccol); rsh = *(const f4*)(r_shift + ccol); }
        }
#pragma unroll
        for (int r = 0; r < 4; ++r) {
            int row = R0 + rq * 4 + r;
            if (row < n) {
                f4 val = acc[r];
                if constexpr (SCALED_BIAS) { float cv = rowscale[row]; val += b4 * cv; }
                else                        { val += b4; }
                if constexpr (RESID) {
                    f4 rv = *(const f4*)(resid + (size_t)row * EMB + ccol);
                    if (r_scale) rv = rv * rsc + rsh;
                    val += rv;
                }
                if constexpr (GELU_OUT) {
#pragma unroll
                    for (int j = 0; j < 4; ++j) {
                        float xg = val[j];
                        val[j] = 0.5f * xg * (1.0f + erff(xg * 0.70710678f));
                    }
                }
                if constexpr (OUT_BF16) {
                    __hip_bfloat16* ob = (__hip_bfloat16*)outv;
                    union { ushort4 u; __hip_bfloat16 h[4]; } pk;
#pragma unroll
                    for (int j = 0; j < 4; ++j) pk.h[j] = __float2bfloat16(val[j]);
                    *(ushort4*)(ob + (size_t)row * OCtot + ccol) = pk.u;
                } else {
                    *(f4*)((float*)outv + (size_t)row * OCtot + ccol) = val;
                }
            }
        }
    }
}

// ---------------------------------------------------------------------------
// Attention: one wave per node. lane = (h,g) in 8x8.
// ---------------------------------------------------------------------------
__global__ void attn_kernel(const float* __restrict__ q, const float* __restrict__ ks,
                            const float* __restrict__ v, const float* __restrict__ cnt,
                            float* __restrict__ out, int n) {
    int wavesPerBlock = blockDim.x >> 6;
    int wid = blockIdx.x * wavesPerBlock + (threadIdx.x >> 6);
    int lane = threadIdx.x & 63;
    int totalWaves = gridDim.x * wavesPerBlock;
    int h = lane >> 3, g = lane & 7;
    for (int node = wid; node < n; node += totalWaves) {
        const f4* q4 = (const f4*)(q + (size_t)node * EMB + h * DH);
        const f4* k4 = (const f4*)(ks + (size_t)node * EMB + g * DH);
        float s = 0.f;
#pragma unroll
        for (int i = 0; i < 4; ++i) {
            f4 a = q4[i], b = k4[i];
            s += a[0] * b[0] + a[1] * b[1] + a[2] * b[2] + a[3] * b[3];
        }
        float c = cnt[node];
        s *= 1.0f / fmaxf(c, 1.0f);
        float m = s;
#pragma unroll
        for (int off = 1; off < 8; off <<= 1) m = fmaxf(m, __shfl_xor(m, off, 64));
        float e = __expf(s - m);
        float sum = e;
#pragma unroll
        for (int off = 1; off < 8; off <<= 1) sum += __shfl_xor(sum, off, 64);
        float p = e / sum;
        float o0 = 0.f, o1 = 0.f;
        int d0 = g * 2;
#pragma unroll
        for (int gg = 0; gg < 8; ++gg) {
            float pg = __shfl(p, h * 8 + gg, 64);
            const float2 vv = *(const float2*)(v + (size_t)node * EMB + gg * DH + d0);
            o0 += pg * vv.x; o1 += pg * vv.y;
        }
        *(float2*)(out + (size_t)node * EMB + h * DH + d0) = make_float2(o0, o1);
    }
}

// ---------------------------------------------------------------------------
// BatchNorm helpers
// ---------------------------------------------------------------------------
__global__ void bn_stats(const float* __restrict__ Y, float* __restrict__ sums, int n) {
    int c = threadIdx.x & 127;
    int rp = threadIdx.x >> 7;
    int r0 = blockIdx.x * 2 + rp;
    int stride = gridDim.x * 2;
    float s = 0.f, sq = 0.f;
    for (int r = r0; r < n; r += stride) {
        float vv = Y[(size_t)r * EMB + c];
        s += vv; sq += vv * vv;
    }
    unsafeAtomicAdd(&sums[c], s);
    unsafeAtomicAdd(&sums[128 + c], sq);
}

__global__ void bn_finalize(const float* __restrict__ sums, float* __restrict__ scsh,
                            const float* __restrict__ g, const float* __restrict__ be, int n) {
    int c = threadIdx.x;
    float invn = 1.0f / (float)n;
    float mean = sums[c] * invn;
    float var = sums[128 + c] * invn - mean * mean;
    var = fmaxf(var, 0.f);
    float sc = g[c] * rsqrtf(var + 1e-5f);
    scsh[c] = sc;
    scsh[128 + c] = be[c] - mean * sc;
}

__global__ void bn_apply(float* __restrict__ Y, const float* __restrict__ scsh, size_t total4) {
    size_t stride = (size_t)gridDim.x * blockDim.x;
    for (size_t i = (size_t)blockIdx.x * blockDim.x + threadIdx.x; i < total4; i += stride) {
        f4 vv = ((f4*)Y)[i];
        int c = (int)((i * 4) & 127);
#pragma unroll
        for (int j = 0; j < 4; ++j) vv[j] = vv[j] * scsh[c + j] + scsh[128 + c + j];
        ((f4*)Y)[i] = vv;
    }
}

// ---------------------------------------------------------------------------
extern "C" void kernel_launch(void* const* d_in, const int* in_sizes, int n_in,
                              void* d_out, int out_size, void* d_ws, size_t ws_size,
                              hipStream_t stream) {
    const float* x   = (const float*)d_in[0];
    const float* wq  = (const float*)d_in[1];
    const float* bq  = (const float*)d_in[2];
    const float* wk  = (const float*)d_in[3];
    const float* bk  = (const float*)d_in[4];
    const float* wv  = (const float*)d_in[5];
    const float* bv  = (const float*)d_in[6];
    const float* wo  = (const float*)d_in[7];
    const float* bo  = (const float*)d_in[8];
    const float* w1  = (const float*)d_in[9];
    const float* b1  = (const float*)d_in[10];
    const float* w2  = (const float*)d_in[11];
    const float* b2  = (const float*)d_in[12];
    const float* g1  = (const float*)d_in[13];
    const float* be1 = (const float*)d_in[14];
    const float* g2  = (const float*)d_in[15];
    const float* be2 = (const float*)d_in[16];
    const int* edge  = (const int*)d_in[17];

    int n = in_sizes[0] / EMB;      // 50000
    int E = in_sizes[17] / 2;       // 800000

    // workspace layout (4-byte elements)
    float* wsf  = (float*)d_ws;
    unsigned* cnt_u = (unsigned*)wsf;                 // 65536
    float*  cntf  = wsf + 65536;                      // 65536
    int*    off   = (int*)(wsf + 2 * 65536);          // 65536
    int*    offw  = (int*)(wsf + 3 * 65536);          // 65536
    int*    sortedB = (int*)(wsf + 4 * 65536);        // E
    float*  q     = wsf + 4 * 65536 + E;              // n*128
    float*  k     = q + (size_t)n * EMB;              // n*128
    float*  v     = k + (size_t)n * EMB;              // n*128
    float*  ksum  = v + (size_t)n * EMB;              // n*128
    float*  stats = ksum + (size_t)n * EMB;           // 1024
    float*  attno = k;                                // reuse (k dead after gather)
    float*  y1    = q;                                // reuse (q dead after attention)
    __hip_bfloat16* hbuf = (__hip_bfloat16*)v;        // n*512 bf16 spans v+ksum (dead)
    float*  y2 = (float*)d_out;                       // BN2 applied in place at the end

    hipMemsetAsync(cnt_u, 0, 65536 * sizeof(unsigned), stream);
    hipMemsetAsync(stats, 0, 1024 * sizeof(float), stream);

    // counting sort of edges by A
    hist_kernel<<<2048, 256, 0, stream>>>(edge, cnt_u, E);
    scan_kernel<<<1, 1024, 0, stream>>>(cnt_u, off, offw, cntf, n);
    place_kernel<<<2048, 256, 0, stream>>>(edge, offw, sortedB, E);

    dim3 grd(512, 1);
    // q = x@wq + bq ; k = x@wk + bk ; v = x@wv + bv
    gemm_k<128, false, false, false, false, false, false><<<grd, 256, 0, stream>>>(
        x, wq, bq, nullptr, nullptr, nullptr, nullptr, nullptr, nullptr, q, n, EMB);
    gemm_k<128, false, false, false, false, false, false><<<grd, 256, 0, stream>>>(
        x, wk, bk, nullptr, nullptr, nullptr, nullptr, nullptr, nullptr, k, n, EMB);
    gemm_k<128, false, false, false, false, false, false><<<grd, 256, 0, stream>>>(
        x, wv, bv, nullptr, nullptr, nullptr, nullptr, nullptr, nullptr, v, n, EMB);

    // ksum[n] = sum of k rows of neighbors (includes cnt*bk automatically)
    gather_kernel<<<2048, 256, 0, stream>>>(k, off, cnt_u, sortedB, ksum, n);

    attn_kernel<<<512, 256, 0, stream>>>(q, ksum, v, cntf, attno, n);

    // y1 = attno@wo + bo + x
    gemm_k<128, false, false, false, false, false, true><<<grd, 256, 0, stream>>>(
        attno, wo, bo, nullptr, nullptr, nullptr, x, nullptr, nullptr, y1, n, EMB);

    bn_stats<<<512, 256, 0, stream>>>(y1, stats, n);
    bn_finalize<<<1, 128, 0, stream>>>(stats, stats + 256, g1, be1, n);

    // h = gelu(xn1@w1 + b1), bf16 out; xn1 applied on the fly from y1
    dim3 grd4(512, 4);
    gemm_k<128, false, false, true, true, true, false><<<grd4, 256, 0, stream>>>(
        y1, w1, b1, nullptr, stats + 256, stats + 384, nullptr, nullptr, nullptr, hbuf, n, HID);

    // y2 = h@w2 + b2 + xn1
    gemm_k<512, false, true, false, false, false, true><<<grd, 256, 0, stream>>>(
        hbuf, w2, b2, nullptr, nullptr, nullptr, y1, stats + 256, stats + 384, y2, n, EMB);

    bn_stats<<<512, 256, 0, stream>>>(y2, stats + 512, n);
    bn_finalize<<<1, 128, 0, stream>>>(stats + 512, stats + 768, g2, be2, n);
    bn_apply<<<512, 256, 0, stream>>>(y2, stats + 768, (size_t)n * EMB / 4);
}

// Round 4
// 653.065 us; speedup vs baseline: 1.4073x; 1.2618x over previous
//
#include <hip/hip_runtime.h>
#include <hip/hip_bf16.h>

typedef float f4 __attribute__((ext_vector_type(4)));
typedef short bh8 __attribute__((ext_vector_type(8)));   // 8 bf16 (4 VGPRs)

#define EMB 128
#define HID 512

__device__ __forceinline__ float bfbits2f(unsigned int lo16) {
    unsigned int u = lo16 << 16;
    return __builtin_bit_cast(float, u);
}
__device__ __forceinline__ short f2bf(float f) {
    __hip_bfloat16 h = __float2bfloat16(f);
    return __builtin_bit_cast(short, h);
}
__device__ __forceinline__ float bdot2(unsigned a, unsigned b) {
    return bfbits2f(a & 0xffffu) * bfbits2f(b & 0xffffu) + bfbits2f(a >> 16) * bfbits2f(b >> 16);
}

// ---------------------------------------------------------------------------
// Counting sort of edges by destination A.
// ---------------------------------------------------------------------------
__global__ void hist_kernel(const int* __restrict__ edge, unsigned* __restrict__ cnt, int E) {
    int stride = gridDim.x * blockDim.x;
    for (int e = blockIdx.x * blockDim.x + threadIdx.x; e < E; e += stride)
        atomicAdd(&cnt[edge[e]], 1u);
}

__global__ void scan_kernel(const unsigned* __restrict__ cnt, int* __restrict__ off,
                            int* __restrict__ offw, float* __restrict__ cntf, int n) {
    __shared__ int part[1024];
    int tid = threadIdx.x;
    int chunk = (n + 1023) / 1024;
    int base = tid * chunk;
    int s = 0;
    for (int i = 0; i < chunk; ++i) {
        int idx = base + i;
        if (idx < n) s += (int)cnt[idx];
    }
    part[tid] = s;
    __syncthreads();
    for (int d = 1; d < 1024; d <<= 1) {
        int t = (tid >= d) ? part[tid - d] : 0;
        __syncthreads();
        part[tid] += t;
        __syncthreads();
    }
    int run = part[tid] - s;
    for (int i = 0; i < chunk; ++i) {
        int idx = base + i;
        if (idx < n) {
            int c = (int)cnt[idx];
            off[idx] = run;
            offw[idx] = run;
            cntf[idx] = (float)c;
            run += c;
        }
    }
}

__global__ void place_kernel(const int* __restrict__ edge, int* __restrict__ offw,
                             int* __restrict__ sortedB, int E) {
    int stride = gridDim.x * blockDim.x;
    for (int e = blockIdx.x * blockDim.x + threadIdx.x; e < E; e += stride) {
        int a = edge[e];
        int pos = atomicAdd(&offw[a], 1);
        sortedB[pos] = edge[E + e];
    }
}

// ---------------------------------------------------------------------------
// Prep: fp32 -> bf16 conversions
// ---------------------------------------------------------------------------
__global__ void convert_x(const float* __restrict__ x, short* __restrict__ xb, size_t total8) {
    size_t stride = (size_t)gridDim.x * blockDim.x;
    for (size_t i = (size_t)blockIdx.x * blockDim.x + threadIdx.x; i < total8; i += stride) {
        size_t base = i * 8;
        f4 lo = *(const f4*)(x + base);
        f4 hi = *(const f4*)(x + base + 4);
        bh8 o;
        o[0] = f2bf(lo[0]); o[1] = f2bf(lo[1]); o[2] = f2bf(lo[2]); o[3] = f2bf(lo[3]);
        o[4] = f2bf(hi[0]); o[5] = f2bf(hi[1]); o[6] = f2bf(hi[2]); o[7] = f2bf(hi[3]);
        *(bh8*)(xb + base) = o;
    }
}

// wt[c][k] = bf16(w[k][c]); w is [K][OC].
__global__ void prep_wt(const float* __restrict__ w, short* __restrict__ wt, int K, int OC) {
    int id = blockIdx.x * blockDim.x + threadIdx.x;
    if (id < K * OC) {
        int k = id / OC, c = id % OC;
        wt[(size_t)c * K + k] = f2bf(w[id]);
    }
}

__global__ void concat_bias(const float* __restrict__ bq, const float* __restrict__ bk,
                            const float* __restrict__ bv, float* __restrict__ bqkv) {
    int t = threadIdx.x;
    bqkv[t] = bq[t];
    bqkv[128 + t] = bk[t];
    bqkv[256 + t] = bv[t];
}

// ---------------------------------------------------------------------------
// MFMA GEMM: out[r, c] = sum_k X[r,k] * Wt[c,k]  (+ fused epilogues)
// Block: 256 threads = 4 waves; wave = 16 rows x 64 cols; block = 64 rows.
// Wt is [OC][KT] bf16. B frags in registers, A streamed, no LDS.
// Frag maps (v_mfma_f32_16x16x32_bf16): A/B: m|n=lane&15, k=(lane>>4)*8+e;
// C/D: col=lane&15, row=(lane>>4)*4+reg.
// ---------------------------------------------------------------------------
template<int KT, bool IN_BF16, bool INSCALE, bool GELU, bool OUT_BF16, bool RESID, bool RSCALED>
__global__ __launch_bounds__(256) void mfma_gemm(
    const void* __restrict__ Xv, const short* __restrict__ Wt, const float* __restrict__ bias,
    const float* __restrict__ in_sc, const float* __restrict__ in_sh,
    const float* __restrict__ resid, const float* __restrict__ r_sc, const float* __restrict__ r_sh,
    void* __restrict__ outv, int n, int OC)
{
    const int lane = threadIdx.x & 63;
    const int wm = threadIdx.x >> 6;
    const int R0 = blockIdx.x * 64 + wm * 16;
    const int C0 = blockIdx.y * 64;
    const int l15 = lane & 15;
    const int kg = lane >> 4;
    const int rowA = min(R0 + l15, n - 1);

    const float* Xf = (const float*)Xv;
    const short* Xb = (const short*)Xv;

    f4 acc[4];
#pragma unroll
    for (int cf = 0; cf < 4; ++cf) acc[cf] = 0.f;

    constexpr int NCH = KT / 128;
#pragma unroll
    for (int kc = 0; kc < NCH; ++kc) {
        bh8 B[4][4];
#pragma unroll
        for (int cf = 0; cf < 4; ++cf) {
            int col = C0 + cf * 16 + l15;
#pragma unroll
            for (int ks = 0; ks < 4; ++ks)
                B[cf][ks] = *(const bh8*)(Wt + (size_t)col * KT + kc * 128 + ks * 32 + kg * 8);
        }
#pragma unroll
        for (int ks = 0; ks < 4; ++ks) {
            int kbase = kc * 128 + ks * 32 + kg * 8;
            bh8 a;
            if constexpr (IN_BF16) {
                a = *(const bh8*)(Xb + (size_t)rowA * KT + kbase);
            } else {
                f4 lo = *(const f4*)(Xf + (size_t)rowA * KT + kbase);
                f4 hi = *(const f4*)(Xf + (size_t)rowA * KT + kbase + 4);
                if constexpr (INSCALE) {
                    f4 sl = *(const f4*)(in_sc + kbase);
                    f4 sh_ = *(const f4*)(in_sc + kbase + 4);
                    f4 tl = *(const f4*)(in_sh + kbase);
                    f4 th = *(const f4*)(in_sh + kbase + 4);
                    lo = lo * sl + tl;
                    hi = hi * sh_ + th;
                }
                a[0] = f2bf(lo[0]); a[1] = f2bf(lo[1]); a[2] = f2bf(lo[2]); a[3] = f2bf(lo[3]);
                a[4] = f2bf(hi[0]); a[5] = f2bf(hi[1]); a[6] = f2bf(hi[2]); a[7] = f2bf(hi[3]);
            }
#pragma unroll
            for (int cf = 0; cf < 4; ++cf)
                acc[cf] = __builtin_amdgcn_mfma_f32_16x16x32_bf16(a, B[cf][ks], acc[cf], 0, 0, 0);
        }
    }

    // epilogue
#pragma unroll
    for (int cf = 0; cf < 4; ++cf) {
        int col = C0 + cf * 16 + l15;
        float b = bias[col];
        float rs = 0.f, rh = 0.f;
        if constexpr (RSCALED) { rs = r_sc[col]; rh = r_sh[col]; }
#pragma unroll
        for (int i = 0; i < 4; ++i) {
            int row = R0 + kg * 4 + i;
            if (row < n) {
                float val = acc[cf][i] + b;
                if constexpr (RESID) {
                    float rv = resid[(size_t)row * EMB + col];
                    if constexpr (RSCALED) rv = rv * rs + rh;
                    val += rv;
                }
                if constexpr (GELU) val = 0.5f * val * (1.0f + erff(val * 0.70710678f));
                if constexpr (OUT_BF16) ((short*)outv)[(size_t)row * OC + col] = f2bf(val);
                else                    ((float*)outv)[(size_t)row * OC + col] = val;
            }
        }
    }
}

// ---------------------------------------------------------------------------
// Gather: ksum[n,:] = sum over sorted neighbor list of k rows (bf16 in qkv).
// One wave per node; lane covers cols 2*lane, 2*lane+1.
// ---------------------------------------------------------------------------
__global__ void gather_kernel(const short* __restrict__ qkv, const int* __restrict__ off,
                              const unsigned* __restrict__ cnt, const int* __restrict__ sortedB,
                              short* __restrict__ ksum, int n) {
    int wid = (int)((blockIdx.x * blockDim.x + threadIdx.x) >> 6);
    int lane = threadIdx.x & 63;
    int nw = (gridDim.x * blockDim.x) >> 6;
    for (int node = wid; node < n; node += nw) {
        int start = off[node];
        int deg = (int)cnt[node];
        float a0 = 0.f, a1 = 0.f;
        int j = 0;
        for (; j + 4 <= deg; j += 4) {
            int b0 = sortedB[start + j + 0];
            int b1 = sortedB[start + j + 1];
            int b2 = sortedB[start + j + 2];
            int b3 = sortedB[start + j + 3];
            unsigned u0 = *(const unsigned*)(qkv + (size_t)b0 * 384 + 128 + 2 * lane);
            unsigned u1 = *(const unsigned*)(qkv + (size_t)b1 * 384 + 128 + 2 * lane);
            unsigned u2 = *(const unsigned*)(qkv + (size_t)b2 * 384 + 128 + 2 * lane);
            unsigned u3 = *(const unsigned*)(qkv + (size_t)b3 * 384 + 128 + 2 * lane);
            a0 += (bfbits2f(u0 & 0xffffu) + bfbits2f(u1 & 0xffffu)) + (bfbits2f(u2 & 0xffffu) + bfbits2f(u3 & 0xffffu));
            a1 += (bfbits2f(u0 >> 16) + bfbits2f(u1 >> 16)) + (bfbits2f(u2 >> 16) + bfbits2f(u3 >> 16));
        }
        for (; j < deg; ++j) {
            int b = sortedB[start + j];
            unsigned u = *(const unsigned*)(qkv + (size_t)b * 384 + 128 + 2 * lane);
            a0 += bfbits2f(u & 0xffffu);
            a1 += bfbits2f(u >> 16);
        }
        unsigned pk = (unsigned)(unsigned short)f2bf(a0) | ((unsigned)(unsigned short)f2bf(a1) << 16);
        *(unsigned*)(ksum + (size_t)node * EMB + 2 * lane) = pk;
    }
}

// ---------------------------------------------------------------------------
// Attention: one wave per node. lane = (h,g) in 8x8. All bf16 in, bf16 out.
// ---------------------------------------------------------------------------
__global__ void attn_kernel(const short* __restrict__ qkv, const short* __restrict__ ksum,
                            const float* __restrict__ cnt, short* __restrict__ attno, int n) {
    int wavesPerBlock = blockDim.x >> 6;
    int wid = blockIdx.x * wavesPerBlock + (threadIdx.x >> 6);
    int lane = threadIdx.x & 63;
    int totalWaves = gridDim.x * wavesPerBlock;
    int h = lane >> 3, g = lane & 7;
    for (int node = wid; node < n; node += totalWaves) {
        const short* qp = qkv + (size_t)node * 384 + h * 16;
        const short* kp = ksum + (size_t)node * EMB + g * 16;
        uint4 qa = *(const uint4*)qp;
        uint4 qb = *(const uint4*)(qp + 8);
        uint4 ka = *(const uint4*)kp;
        uint4 kb = *(const uint4*)(kp + 8);
        float s = bdot2(qa.x, ka.x) + bdot2(qa.y, ka.y) + bdot2(qa.z, ka.z) + bdot2(qa.w, ka.w)
                + bdot2(qb.x, kb.x) + bdot2(qb.y, kb.y) + bdot2(qb.z, kb.z) + bdot2(qb.w, kb.w);
        float c = cnt[node];
        s *= 1.0f / fmaxf(c, 1.0f);
        float m = s;
#pragma unroll
        for (int off = 1; off < 8; off <<= 1) m = fmaxf(m, __shfl_xor(m, off, 64));
        float e = __expf(s - m);
        float sum = e;
#pragma unroll
        for (int off = 1; off < 8; off <<= 1) sum += __shfl_xor(sum, off, 64);
        float p = e / sum;
        float o0 = 0.f, o1 = 0.f;
        int d0 = g * 2;
#pragma unroll
        for (int gg = 0; gg < 8; ++gg) {
            float pg = __shfl(p, h * 8 + gg, 64);
            unsigned vv = *(const unsigned*)(qkv + (size_t)node * 384 + 256 + gg * 16 + d0);
            o0 += pg * bfbits2f(vv & 0xffffu);
            o1 += pg * bfbits2f(vv >> 16);
        }
        unsigned pk = (unsigned)(unsigned short)f2bf(o0) | ((unsigned)(unsigned short)f2bf(o1) << 16);
        *(unsigned*)(attno + (size_t)node * EMB + h * 16 + d0) = pk;
    }
}

// ---------------------------------------------------------------------------
// BatchNorm helpers (fp32)
// ---------------------------------------------------------------------------
__global__ void bn_stats(const float* __restrict__ Y, float* __restrict__ sums, int n) {
    int c = threadIdx.x & 127;
    int rp = threadIdx.x >> 7;
    int r0 = blockIdx.x * 2 + rp;
    int stride = gridDim.x * 2;
    float s = 0.f, sq = 0.f;
    for (int r = r0; r < n; r += stride) {
        float vv = Y[(size_t)r * EMB + c];
        s += vv; sq += vv * vv;
    }
    unsafeAtomicAdd(&sums[c], s);
    unsafeAtomicAdd(&sums[128 + c], sq);
}

__global__ void bn_finalize(const float* __restrict__ sums, float* __restrict__ scsh,
                            const float* __restrict__ g, const float* __restrict__ be, int n) {
    int c = threadIdx.x;
    float invn = 1.0f / (float)n;
    float mean = sums[c] * invn;
    float var = sums[128 + c] * invn - mean * mean;
    var = fmaxf(var, 0.f);
    float sc = g[c] * rsqrtf(var + 1e-5f);
    scsh[c] = sc;
    scsh[128 + c] = be[c] - mean * sc;
}

__global__ void bn_apply(float* __restrict__ Y, const float* __restrict__ scsh, size_t total4) {
    size_t stride = (size_t)gridDim.x * blockDim.x;
    for (size_t i = (size_t)blockIdx.x * blockDim.x + threadIdx.x; i < total4; i += stride) {
        f4 vv = ((f4*)Y)[i];
        int c = (int)((i * 4) & 127);
#pragma unroll
        for (int j = 0; j < 4; ++j) vv[j] = vv[j] * scsh[c + j] + scsh[128 + c + j];
        ((f4*)Y)[i] = vv;
    }
}

// ---------------------------------------------------------------------------
extern "C" void kernel_launch(void* const* d_in, const int* in_sizes, int n_in,
                              void* d_out, int out_size, void* d_ws, size_t ws_size,
                              hipStream_t stream) {
    const float* x   = (const float*)d_in[0];
    const float* wq  = (const float*)d_in[1];
    const float* bq  = (const float*)d_in[2];
    const float* wk  = (const float*)d_in[3];
    const float* bk  = (const float*)d_in[4];
    const float* wv  = (const float*)d_in[5];
    const float* bv  = (const float*)d_in[6];
    const float* wo  = (const float*)d_in[7];
    const float* bo  = (const float*)d_in[8];
    const float* w1  = (const float*)d_in[9];
    const float* b1  = (const float*)d_in[10];
    const float* w2  = (const float*)d_in[11];
    const float* b2  = (const float*)d_in[12];
    const float* g1  = (const float*)d_in[13];
    const float* be1 = (const float*)d_in[14];
    const float* g2  = (const float*)d_in[15];
    const float* be2 = (const float*)d_in[16];
    const int* edge  = (const int*)d_in[17];

    int n = in_sizes[0] / EMB;      // 50000
    int E = in_sizes[17] / 2;       // 800000

    // workspace layout (float units)
    float* wsf = (float*)d_ws;
    unsigned* cnt_u = (unsigned*)wsf;                       // 65536
    float*  cntf  = wsf + 65536;                            // 65536
    int*    off   = (int*)(wsf + 2 * 65536);                // 65536
    int*    offw  = (int*)(wsf + 3 * 65536);                // 65536
    int*    sortedB = (int*)(wsf + 4 * 65536);              // E
    float*  base5 = wsf + 4 * 65536 + E;
    short*  qkv   = (short*)base5;                          // n*384 bf16 = n*192 f
    short*  ksum  = (short*)(base5 + (size_t)n * 192);      // n*128 bf16 = n*64 f
    short*  attno = (short*)(base5 + (size_t)n * 256);      // n*128 bf16 = n*64 f
    float*  y1    = base5 + (size_t)n * 320;                // n*128 f
    short*  xb    = (short*)(y1 + (size_t)n * 128);         // n*128 bf16 = n*64 f
    float*  warea = y1 + (size_t)n * 192;
    short*  wqkvT = (short*)warea;                          // 384*128 bf16
    short*  woT   = wqkvT + 384 * 128;                      // 128*128
    short*  w1T   = woT + 128 * 128;                        // 512*128
    short*  w2T   = w1T + 512 * 128;                        // 128*512
    float*  bqkv  = (float*)(w2T + 128 * 512);              // 384
    float*  stats = bqkv + 384;                             // 1024
    short*  hbuf  = qkv;                                    // n*512 bf16 (spans qkv+ksum, both dead)
    float*  y2    = (float*)d_out;

    hipMemsetAsync(cnt_u, 0, 65536 * sizeof(unsigned), stream);
    hipMemsetAsync(stats, 0, 1024 * sizeof(float), stream);

    // edge counting sort
    hist_kernel<<<2048, 256, 0, stream>>>(edge, cnt_u, E);
    scan_kernel<<<1, 1024, 0, stream>>>(cnt_u, off, offw, cntf, n);
    place_kernel<<<2048, 256, 0, stream>>>(edge, offw, sortedB, E);

    // prep: bf16 conversions
    convert_x<<<3200, 256, 0, stream>>>(x, xb, (size_t)n * EMB / 8);
    prep_wt<<<(128 * 128 + 255) / 256, 256, 0, stream>>>(wq, wqkvT, 128, 128);
    prep_wt<<<(128 * 128 + 255) / 256, 256, 0, stream>>>(wk, wqkvT + 128 * 128, 128, 128);
    prep_wt<<<(128 * 128 + 255) / 256, 256, 0, stream>>>(wv, wqkvT + 256 * 128, 128, 128);
    prep_wt<<<(128 * 128 + 255) / 256, 256, 0, stream>>>(wo, woT, 128, 128);
    prep_wt<<<(128 * 512 + 255) / 256, 256, 0, stream>>>(w1, w1T, 128, 512);
    prep_wt<<<(512 * 128 + 255) / 256, 256, 0, stream>>>(w2, w2T, 512, 128);
    concat_bias<<<1, 128, 0, stream>>>(bq, bk, bv, bqkv);

    int rb = (n + 63) / 64;  // 782

    // qkv = xb @ [wq|wk|wv] + bqkv  (bf16 out, [n][384])
    mfma_gemm<128, true, false, false, true, false, false><<<dim3(rb, 6), 256, 0, stream>>>(
        xb, wqkvT, bqkv, nullptr, nullptr, nullptr, nullptr, nullptr, qkv, n, 384);

    // ksum[n] = sum of k rows of neighbors
    gather_kernel<<<2048, 256, 0, stream>>>(qkv, off, cnt_u, sortedB, ksum, n);

    attn_kernel<<<512, 256, 0, stream>>>(qkv, ksum, cntf, attno, n);

    // y1 = attno@wo + bo + x (fp32 out)
    mfma_gemm<128, true, false, false, false, true, false><<<dim3(rb, 2), 256, 0, stream>>>(
        attno, woT, bo, nullptr, nullptr, x, nullptr, nullptr, y1, n, EMB);

    bn_stats<<<512, 256, 0, stream>>>(y1, stats, n);
    bn_finalize<<<1, 128, 0, stream>>>(stats, stats + 256, g1, be1, n);

    // h = gelu(bn1(y1)@w1 + b1), bf16 out
    mfma_gemm<128, false, true, true, true, false, false><<<dim3(rb, 8), 256, 0, stream>>>(
        y1, w1T, b1, stats + 256, stats + 384, nullptr, nullptr, nullptr, hbuf, n, HID);

    // y2 = h@w2 + b2 + bn1(y1) (fp32 out to d_out)
    mfma_gemm<512, true, false, false, false, true, true><<<dim3(rb, 2), 256, 0, stream>>>(
        hbuf, w2T, b2, nullptr, nullptr, y1, stats + 256, stats + 384, y2, n, EMB);

    bn_stats<<<512, 256, 0, stream>>>(y2, stats + 512, n);
    bn_finalize<<<1, 128, 0, stream>>>(stats + 512, stats + 768, g2, be2, n);
    bn_apply<<<512, 256, 0, stream>>>(y2, stats + 768, (size_t)n * EMB / 4);
}

// Round 5
// 518.619 us; speedup vs baseline: 1.7722x; 1.2592x over previous
//
#include <hip/hip_runtime.h>
#include <hip/hip_bf16.h>

typedef float f4 __attribute__((ext_vector_type(4)));
typedef short bh8 __attribute__((ext_vector_type(8)));   // 8 bf16 (4 VGPRs)

#define EMB 128
#define HID 512

__device__ __forceinline__ float bfbits2f(unsigned int lo16) {
    unsigned int u = lo16 << 16;
    return __builtin_bit_cast(float, u);
}
__device__ __forceinline__ short f2bf(float f) {
    __hip_bfloat16 h = __float2bfloat16(f);
    return __builtin_bit_cast(short, h);
}
__device__ __forceinline__ float bdot2(unsigned a, unsigned b) {
    return bfbits2f(a & 0xffffu) * bfbits2f(b & 0xffffu) + bfbits2f(a >> 16) * bfbits2f(b >> 16);
}

// ---------------------------------------------------------------------------
// Counting sort of edges by destination A.
// ---------------------------------------------------------------------------
__global__ void hist_kernel(const int* __restrict__ edge, unsigned* __restrict__ cnt, int E) {
    int stride = gridDim.x * blockDim.x;
    for (int e = blockIdx.x * blockDim.x + threadIdx.x; e < E; e += stride)
        atomicAdd(&cnt[edge[e]], 1u);
}

// Hierarchical exclusive scan: 256 threads x 4 elements per block.
__global__ void scan_blocks(const unsigned* __restrict__ cnt, int* __restrict__ off,
                            int* __restrict__ bsum, int n) {
    __shared__ int ls[256];
    int tid = threadIdx.x;
    int base = blockIdx.x * 1024 + tid * 4;
    int v0 = 0, v1 = 0, v2 = 0, v3 = 0;
    if (base + 0 < n) v0 = (int)cnt[base + 0];
    if (base + 1 < n) v1 = (int)cnt[base + 1];
    if (base + 2 < n) v2 = (int)cnt[base + 2];
    if (base + 3 < n) v3 = (int)cnt[base + 3];
    int s = v0 + v1 + v2 + v3;
    ls[tid] = s;
    __syncthreads();
    for (int d = 1; d < 256; d <<= 1) {
        int t = (tid >= d) ? ls[tid - d] : 0;
        __syncthreads();
        ls[tid] += t;
        __syncthreads();
    }
    int incl = ls[tid];
    int run = incl - s;  // exclusive prefix of this thread's 4
    if (tid == 255) bsum[blockIdx.x] = incl;
    if (base + 0 < n) { off[base + 0] = run; run += v0; }
    if (base + 1 < n) { off[base + 1] = run; run += v1; }
    if (base + 2 < n) { off[base + 2] = run; run += v2; }
    if (base + 3 < n) { off[base + 3] = run; }
}

// exclusive scan of <=64 block sums, in place (1 wave)
__global__ void scan_bsums(int* __restrict__ bsum, int nb) {
    int lane = threadIdx.x & 63;
    int x = (lane < nb) ? bsum[lane] : 0;
    int orig = x;
#pragma unroll
    for (int o = 1; o < 64; o <<= 1) {
        int t = __shfl_up(x, o, 64);
        if (lane >= o) x += t;
    }
    if (lane < nb) bsum[lane] = x - orig;
}

__global__ void scan_apply(const unsigned* __restrict__ cnt, const int* __restrict__ bsum,
                           int* __restrict__ off, int* __restrict__ offw,
                           float* __restrict__ cntf, int n) {
    int base = blockIdx.x * 1024 + threadIdx.x * 4;
    int add = bsum[blockIdx.x];
#pragma unroll
    for (int i = 0; i < 4; ++i) {
        int idx = base + i;
        if (idx < n) {
            int o = off[idx] + add;
            off[idx] = o;
            offw[idx] = o;
            cntf[idx] = (float)cnt[idx];
        }
    }
}

__global__ void place_kernel(const int* __restrict__ edge, int* __restrict__ offw,
                             int* __restrict__ sortedB, int E) {
    int stride = gridDim.x * blockDim.x;
    for (int e = blockIdx.x * blockDim.x + threadIdx.x; e < E; e += stride) {
        int a = edge[e];
        int pos = atomicAdd(&offw[a], 1);
        sortedB[pos] = edge[E + e];
    }
}

// ---------------------------------------------------------------------------
// Prep: fp32 -> bf16 conversions
// ---------------------------------------------------------------------------
__global__ void convert_x(const float* __restrict__ x, short* __restrict__ xb, size_t total8) {
    size_t stride = (size_t)gridDim.x * blockDim.x;
    for (size_t i = (size_t)blockIdx.x * blockDim.x + threadIdx.x; i < total8; i += stride) {
        size_t base = i * 8;
        f4 lo = *(const f4*)(x + base);
        f4 hi = *(const f4*)(x + base + 4);
        bh8 o;
        o[0] = f2bf(lo[0]); o[1] = f2bf(lo[1]); o[2] = f2bf(lo[2]); o[3] = f2bf(lo[3]);
        o[4] = f2bf(hi[0]); o[5] = f2bf(hi[1]); o[6] = f2bf(hi[2]); o[7] = f2bf(hi[3]);
        *(bh8*)(xb + base) = o;
    }
}

// wt[c][k] = bf16(w[k][c]); w is [K][OC].
__global__ void prep_wt(const float* __restrict__ w, short* __restrict__ wt, int K, int OC) {
    int id = blockIdx.x * blockDim.x + threadIdx.x;
    if (id < K * OC) {
        int k = id / OC, c = id % OC;
        wt[(size_t)c * K + k] = f2bf(w[id]);
    }
}

__global__ void concat_bias(const float* __restrict__ bq, const float* __restrict__ bk,
                            const float* __restrict__ bv, float* __restrict__ bqkv) {
    int t = threadIdx.x;
    bqkv[t] = bq[t];
    bqkv[128 + t] = bk[t];
    bqkv[256 + t] = bv[t];
}

// ---------------------------------------------------------------------------
// MFMA GEMM: out[r, c] = sum_k X[r,k] * Wt[c,k]  (+ fused epilogues)
// Block: 256 threads = 4 waves; wave = 16 rows x 64 cols; block = 64 rows.
// ---------------------------------------------------------------------------
template<int KT, bool IN_BF16, bool INSCALE, bool GELU, bool OUT_BF16, bool RESID, bool RSCALED>
__global__ __launch_bounds__(256) void mfma_gemm(
    const void* __restrict__ Xv, const short* __restrict__ Wt, const float* __restrict__ bias,
    const float* __restrict__ in_sc, const float* __restrict__ in_sh,
    const float* __restrict__ resid, const float* __restrict__ r_sc, const float* __restrict__ r_sh,
    void* __restrict__ outv, int n, int OC)
{
    const int lane = threadIdx.x & 63;
    const int wm = threadIdx.x >> 6;
    const int R0 = blockIdx.x * 64 + wm * 16;
    const int C0 = blockIdx.y * 64;
    const int l15 = lane & 15;
    const int kg = lane >> 4;
    const int rowA = min(R0 + l15, n - 1);

    const float* Xf = (const float*)Xv;
    const short* Xb = (const short*)Xv;

    f4 acc[4];
#pragma unroll
    for (int cf = 0; cf < 4; ++cf) acc[cf] = 0.f;

    constexpr int NCH = KT / 128;
#pragma unroll
    for (int kc = 0; kc < NCH; ++kc) {
        bh8 B[4][4];
#pragma unroll
        for (int cf = 0; cf < 4; ++cf) {
            int col = C0 + cf * 16 + l15;
#pragma unroll
            for (int ks = 0; ks < 4; ++ks)
                B[cf][ks] = *(const bh8*)(Wt + (size_t)col * KT + kc * 128 + ks * 32 + kg * 8);
        }
#pragma unroll
        for (int ks = 0; ks < 4; ++ks) {
            int kbase = kc * 128 + ks * 32 + kg * 8;
            bh8 a;
            if constexpr (IN_BF16) {
                a = *(const bh8*)(Xb + (size_t)rowA * KT + kbase);
            } else {
                f4 lo = *(const f4*)(Xf + (size_t)rowA * KT + kbase);
                f4 hi = *(const f4*)(Xf + (size_t)rowA * KT + kbase + 4);
                if constexpr (INSCALE) {
                    f4 sl = *(const f4*)(in_sc + kbase);
                    f4 sh_ = *(const f4*)(in_sc + kbase + 4);
                    f4 tl = *(const f4*)(in_sh + kbase);
                    f4 th = *(const f4*)(in_sh + kbase + 4);
                    lo = lo * sl + tl;
                    hi = hi * sh_ + th;
                }
                a[0] = f2bf(lo[0]); a[1] = f2bf(lo[1]); a[2] = f2bf(lo[2]); a[3] = f2bf(lo[3]);
                a[4] = f2bf(hi[0]); a[5] = f2bf(hi[1]); a[6] = f2bf(hi[2]); a[7] = f2bf(hi[3]);
            }
#pragma unroll
            for (int cf = 0; cf < 4; ++cf)
                acc[cf] = __builtin_amdgcn_mfma_f32_16x16x32_bf16(a, B[cf][ks], acc[cf], 0, 0, 0);
        }
    }

    // epilogue
#pragma unroll
    for (int cf = 0; cf < 4; ++cf) {
        int col = C0 + cf * 16 + l15;
        float b = bias[col];
        float rs = 0.f, rh = 0.f;
        if constexpr (RSCALED) { rs = r_sc[col]; rh = r_sh[col]; }
#pragma unroll
        for (int i = 0; i < 4; ++i) {
            int row = R0 + kg * 4 + i;
            if (row < n) {
                float val = acc[cf][i] + b;
                if constexpr (RESID) {
                    float rv = resid[(size_t)row * EMB + col];
                    if constexpr (RSCALED) rv = rv * rs + rh;
                    val += rv;
                }
                if constexpr (GELU) val = 0.5f * val * (1.0f + erff(val * 0.70710678f));
                if constexpr (OUT_BF16) ((short*)outv)[(size_t)row * OC + col] = f2bf(val);
                else                    ((float*)outv)[(size_t)row * OC + col] = val;
            }
        }
    }
}

// ---------------------------------------------------------------------------
// Gather: ksum[n,:] = sum over sorted neighbor list of k rows (bf16 in qkv).
// ---------------------------------------------------------------------------
__global__ void gather_kernel(const short* __restrict__ qkv, const int* __restrict__ off,
                              const unsigned* __restrict__ cnt, const int* __restrict__ sortedB,
                              short* __restrict__ ksum, int n) {
    int wid = (int)((blockIdx.x * blockDim.x + threadIdx.x) >> 6);
    int lane = threadIdx.x & 63;
    int nw = (gridDim.x * blockDim.x) >> 6;
    for (int node = wid; node < n; node += nw) {
        int start = off[node];
        int deg = (int)cnt[node];
        float a0 = 0.f, a1 = 0.f;
        int j = 0;
        for (; j + 4 <= deg; j += 4) {
            int b0 = sortedB[start + j + 0];
            int b1 = sortedB[start + j + 1];
            int b2 = sortedB[start + j + 2];
            int b3 = sortedB[start + j + 3];
            unsigned u0 = *(const unsigned*)(qkv + (size_t)b0 * 384 + 128 + 2 * lane);
            unsigned u1 = *(const unsigned*)(qkv + (size_t)b1 * 384 + 128 + 2 * lane);
            unsigned u2 = *(const unsigned*)(qkv + (size_t)b2 * 384 + 128 + 2 * lane);
            unsigned u3 = *(const unsigned*)(qkv + (size_t)b3 * 384 + 128 + 2 * lane);
            a0 += (bfbits2f(u0 & 0xffffu) + bfbits2f(u1 & 0xffffu)) + (bfbits2f(u2 & 0xffffu) + bfbits2f(u3 & 0xffffu));
            a1 += (bfbits2f(u0 >> 16) + bfbits2f(u1 >> 16)) + (bfbits2f(u2 >> 16) + bfbits2f(u3 >> 16));
        }
        for (; j < deg; ++j) {
            int b = sortedB[start + j];
            unsigned u = *(const unsigned*)(qkv + (size_t)b * 384 + 128 + 2 * lane);
            a0 += bfbits2f(u & 0xffffu);
            a1 += bfbits2f(u >> 16);
        }
        unsigned pk = (unsigned)(unsigned short)f2bf(a0) | ((unsigned)(unsigned short)f2bf(a1) << 16);
        *(unsigned*)(ksum + (size_t)node * EMB + 2 * lane) = pk;
    }
}

// ---------------------------------------------------------------------------
// Attention: one wave per node. lane = (h,g) in 8x8. All bf16 in, bf16 out.
// ---------------------------------------------------------------------------
__global__ void attn_kernel(const short* __restrict__ qkv, const short* __restrict__ ksum,
                            const float* __restrict__ cnt, short* __restrict__ attno, int n) {
    int wavesPerBlock = blockDim.x >> 6;
    int wid = blockIdx.x * wavesPerBlock + (threadIdx.x >> 6);
    int lane = threadIdx.x & 63;
    int totalWaves = gridDim.x * wavesPerBlock;
    int h = lane >> 3, g = lane & 7;
    for (int node = wid; node < n; node += totalWaves) {
        const short* qp = qkv + (size_t)node * 384 + h * 16;
        const short* kp = ksum + (size_t)node * EMB + g * 16;
        uint4 qa = *(const uint4*)qp;
        uint4 qb = *(const uint4*)(qp + 8);
        uint4 ka = *(const uint4*)kp;
        uint4 kb = *(const uint4*)(kp + 8);
        float s = bdot2(qa.x, ka.x) + bdot2(qa.y, ka.y) + bdot2(qa.z, ka.z) + bdot2(qa.w, ka.w)
                + bdot2(qb.x, kb.x) + bdot2(qb.y, kb.y) + bdot2(qb.z, kb.z) + bdot2(qb.w, kb.w);
        float c = cnt[node];
        s *= 1.0f / fmaxf(c, 1.0f);
        float m = s;
#pragma unroll
        for (int off = 1; off < 8; off <<= 1) m = fmaxf(m, __shfl_xor(m, off, 64));
        float e = __expf(s - m);
        float sum = e;
#pragma unroll
        for (int off = 1; off < 8; off <<= 1) sum += __shfl_xor(sum, off, 64);
        float p = e / sum;
        float o0 = 0.f, o1 = 0.f;
        int d0 = g * 2;
#pragma unroll
        for (int gg = 0; gg < 8; ++gg) {
            float pg = __shfl(p, h * 8 + gg, 64);
            unsigned vv = *(const unsigned*)(qkv + (size_t)node * 384 + 256 + gg * 16 + d0);
            o0 += pg * bfbits2f(vv & 0xffffu);
            o1 += pg * bfbits2f(vv >> 16);
        }
        unsigned pk = (unsigned)(unsigned short)f2bf(o0) | ((unsigned)(unsigned short)f2bf(o1) << 16);
        *(unsigned*)(attno + (size_t)node * EMB + h * 16 + d0) = pk;
    }
}

// ---------------------------------------------------------------------------
// BatchNorm helpers (fp32)
// ---------------------------------------------------------------------------
__global__ void bn_stats(const float* __restrict__ Y, float* __restrict__ sums, int n) {
    int c = threadIdx.x & 127;
    int rp = threadIdx.x >> 7;
    int r0 = blockIdx.x * 2 + rp;
    int stride = gridDim.x * 2;
    float s = 0.f, sq = 0.f;
    for (int r = r0; r < n; r += stride) {
        float vv = Y[(size_t)r * EMB + c];
        s += vv; sq += vv * vv;
    }
    unsafeAtomicAdd(&sums[c], s);
    unsafeAtomicAdd(&sums[128 + c], sq);
}

__global__ void bn_finalize(const float* __restrict__ sums, float* __restrict__ scsh,
                            const float* __restrict__ g, const float* __restrict__ be, int n) {
    int c = threadIdx.x;
    float invn = 1.0f / (float)n;
    float mean = sums[c] * invn;
    float var = sums[128 + c] * invn - mean * mean;
    var = fmaxf(var, 0.f);
    float sc = g[c] * rsqrtf(var + 1e-5f);
    scsh[c] = sc;
    scsh[128 + c] = be[c] - mean * sc;
}

__global__ void bn_apply(float* __restrict__ Y, const float* __restrict__ scsh, size_t total4) {
    size_t stride = (size_t)gridDim.x * blockDim.x;
    for (size_t i = (size_t)blockIdx.x * blockDim.x + threadIdx.x; i < total4; i += stride) {
        f4 vv = ((f4*)Y)[i];
        int c = (int)((i * 4) & 127);
#pragma unroll
        for (int j = 0; j < 4; ++j) vv[j] = vv[j] * scsh[c + j] + scsh[128 + c + j];
        ((f4*)Y)[i] = vv;
    }
}

// ---------------------------------------------------------------------------
extern "C" void kernel_launch(void* const* d_in, const int* in_sizes, int n_in,
                              void* d_out, int out_size, void* d_ws, size_t ws_size,
                              hipStream_t stream) {
    const float* x   = (const float*)d_in[0];
    const float* wq  = (const float*)d_in[1];
    const float* bq  = (const float*)d_in[2];
    const float* wk  = (const float*)d_in[3];
    const float* bk  = (const float*)d_in[4];
    const float* wv  = (const float*)d_in[5];
    const float* bv  = (const float*)d_in[6];
    const float* wo  = (const float*)d_in[7];
    const float* bo  = (const float*)d_in[8];
    const float* w1  = (const float*)d_in[9];
    const float* b1  = (const float*)d_in[10];
    const float* w2  = (const float*)d_in[11];
    const float* b2  = (const float*)d_in[12];
    const float* g1  = (const float*)d_in[13];
    const float* be1 = (const float*)d_in[14];
    const float* g2  = (const float*)d_in[15];
    const float* be2 = (const float*)d_in[16];
    const int* edge  = (const int*)d_in[17];

    int n = in_sizes[0] / EMB;      // 50000
    int E = in_sizes[17] / 2;       // 800000

    // workspace layout (float units)
    float* wsf = (float*)d_ws;
    unsigned* cnt_u = (unsigned*)wsf;                       // 65536
    float*  cntf  = wsf + 65536;                            // 65536
    int*    off   = (int*)(wsf + 2 * 65536);                // 65536
    int*    offw  = (int*)(wsf + 3 * 65536);                // 65536
    int*    bsum  = (int*)(wsf + 4 * 65536);                // 64
    int*    sortedB = (int*)(wsf + 4 * 65536 + 64);         // E
    float*  base5 = wsf + 4 * 65536 + 64 + E;
    short*  qkv   = (short*)base5;                          // n*384 bf16 = n*192 f
    short*  ksum  = (short*)(base5 + (size_t)n * 192);      // n*128 bf16 = n*64 f
    short*  attno = (short*)(base5 + (size_t)n * 256);      // n*128 bf16 = n*64 f
    float*  y1    = base5 + (size_t)n * 320;                // n*128 f
    short*  xb    = (short*)(y1 + (size_t)n * 128);         // n*128 bf16 = n*64 f
    float*  warea = y1 + (size_t)n * 192;
    short*  wqkvT = (short*)warea;                          // 384*128 bf16
    short*  woT   = wqkvT + 384 * 128;                      // 128*128
    short*  w1T   = woT + 128 * 128;                        // 512*128
    short*  w2T   = w1T + 512 * 128;                        // 128*512
    float*  bqkv  = (float*)(w2T + 128 * 512);              // 384
    float*  stats = bqkv + 384;                             // 1024
    short*  hbuf  = qkv;                                    // n*512 bf16 (spans qkv+ksum, both dead)
    float*  y2    = (float*)d_out;

    hipMemsetAsync(cnt_u, 0, 65536 * sizeof(unsigned), stream);
    hipMemsetAsync(stats, 0, 1024 * sizeof(float), stream);

    // edge counting sort
    int nb = (n + 1023) / 1024;  // 49
    hist_kernel<<<2048, 256, 0, stream>>>(edge, cnt_u, E);
    scan_blocks<<<nb, 256, 0, stream>>>(cnt_u, off, bsum, n);
    scan_bsums<<<1, 64, 0, stream>>>(bsum, nb);
    scan_apply<<<nb, 256, 0, stream>>>(cnt_u, bsum, off, offw, cntf, n);
    place_kernel<<<2048, 256, 0, stream>>>(edge, offw, sortedB, E);

    // prep: bf16 conversions
    convert_x<<<3200, 256, 0, stream>>>(x, xb, (size_t)n * EMB / 8);
    prep_wt<<<(128 * 128 + 255) / 256, 256, 0, stream>>>(wq, wqkvT, 128, 128);
    prep_wt<<<(128 * 128 + 255) / 256, 256, 0, stream>>>(wk, wqkvT + 128 * 128, 128, 128);
    prep_wt<<<(128 * 128 + 255) / 256, 256, 0, stream>>>(wv, wqkvT + 256 * 128, 128, 128);
    prep_wt<<<(128 * 128 + 255) / 256, 256, 0, stream>>>(wo, woT, 128, 128);
    prep_wt<<<(128 * 512 + 255) / 256, 256, 0, stream>>>(w1, w1T, 128, 512);
    prep_wt<<<(512 * 128 + 255) / 256, 256, 0, stream>>>(w2, w2T, 512, 128);
    concat_bias<<<1, 128, 0, stream>>>(bq, bk, bv, bqkv);

    int rb = (n + 63) / 64;  // 782

    // qkv = xb @ [wq|wk|wv] + bqkv  (bf16 out, [n][384])
    mfma_gemm<128, true, false, false, true, false, false><<<dim3(rb, 6), 256, 0, stream>>>(
        xb, wqkvT, bqkv, nullptr, nullptr, nullptr, nullptr, nullptr, qkv, n, 384);

    // ksum[n] = sum of k rows of neighbors
    gather_kernel<<<2048, 256, 0, stream>>>(qkv, off, cnt_u, sortedB, ksum, n);

    attn_kernel<<<512, 256, 0, stream>>>(qkv, ksum, cntf, attno, n);

    // y1 = attno@wo + bo + x (fp32 out)
    mfma_gemm<128, true, false, false, false, true, false><<<dim3(rb, 2), 256, 0, stream>>>(
        attno, woT, bo, nullptr, nullptr, x, nullptr, nullptr, y1, n, EMB);

    bn_stats<<<512, 256, 0, stream>>>(y1, stats, n);
    bn_finalize<<<1, 128, 0, stream>>>(stats, stats + 256, g1, be1, n);

    // h = gelu(bn1(y1)@w1 + b1), bf16 out
    mfma_gemm<128, false, true, true, true, false, false><<<dim3(rb, 8), 256, 0, stream>>>(
        y1, w1T, b1, stats + 256, stats + 384, nullptr, nullptr, nullptr, hbuf, n, HID);

    // y2 = h@w2 + b2 + bn1(y1) (fp32 out to d_out)
    mfma_gemm<512, true, false, false, false, true, true><<<dim3(rb, 2), 256, 0, stream>>>(
        hbuf, w2T, b2, nullptr, nullptr, y1, stats + 256, stats + 384, y2, n, EMB);

    bn_stats<<<512, 256, 0, stream>>>(y2, stats + 512, n);
    bn_finalize<<<1, 128, 0, stream>>>(stats + 512, stats + 768, g2, be2, n);
    bn_apply<<<512, 256, 0, stream>>>(y2, stats + 768, (size_t)n * EMB / 4);
}

// Round 6
// 446.282 us; speedup vs baseline: 2.0594x; 1.1621x over previous
//
#include <hip/hip_runtime.h>
#include <hip/hip_bf16.h>

typedef float f4 __attribute__((ext_vector_type(4)));
typedef short bh8 __attribute__((ext_vector_type(8)));   // 8 bf16 (4 VGPRs)

#define EMB 128
#define HID 512

__device__ __forceinline__ float bfbits2f(unsigned int lo16) {
    unsigned int u = lo16 << 16;
    return __builtin_bit_cast(float, u);
}
__device__ __forceinline__ short f2bf(float f) {
    __hip_bfloat16 h = __float2bfloat16(f);
    return __builtin_bit_cast(short, h);
}
__device__ __forceinline__ float bdot2(unsigned a, unsigned b) {
    return bfbits2f(a & 0xffffu) * bfbits2f(b & 0xffffu) + bfbits2f(a >> 16) * bfbits2f(b >> 16);
}

// ---------------------------------------------------------------------------
// Counting sort of edges by destination A.
// ---------------------------------------------------------------------------
__global__ void hist_kernel(const int* __restrict__ edge, unsigned* __restrict__ cnt, int E) {
    int stride = gridDim.x * blockDim.x;
    for (int e = blockIdx.x * blockDim.x + threadIdx.x; e < E; e += stride)
        atomicAdd(&cnt[edge[e]], 1u);
}

// Hierarchical exclusive scan: 256 threads x 4 elements per block.
__global__ void scan_blocks(const unsigned* __restrict__ cnt, int* __restrict__ off,
                            int* __restrict__ bsum, int n) {
    __shared__ int ls[256];
    int tid = threadIdx.x;
    int base = blockIdx.x * 1024 + tid * 4;
    int v0 = 0, v1 = 0, v2 = 0, v3 = 0;
    if (base + 0 < n) v0 = (int)cnt[base + 0];
    if (base + 1 < n) v1 = (int)cnt[base + 1];
    if (base + 2 < n) v2 = (int)cnt[base + 2];
    if (base + 3 < n) v3 = (int)cnt[base + 3];
    int s = v0 + v1 + v2 + v3;
    ls[tid] = s;
    __syncthreads();
    for (int d = 1; d < 256; d <<= 1) {
        int t = (tid >= d) ? ls[tid - d] : 0;
        __syncthreads();
        ls[tid] += t;
        __syncthreads();
    }
    int incl = ls[tid];
    int run = incl - s;
    if (tid == 255) bsum[blockIdx.x] = incl;
    if (base + 0 < n) { off[base + 0] = run; run += v0; }
    if (base + 1 < n) { off[base + 1] = run; run += v1; }
    if (base + 2 < n) { off[base + 2] = run; run += v2; }
    if (base + 3 < n) { off[base + 3] = run; }
}

__global__ void scan_bsums(int* __restrict__ bsum, int nb) {
    int lane = threadIdx.x & 63;
    int x = (lane < nb) ? bsum[lane] : 0;
    int orig = x;
#pragma unroll
    for (int o = 1; o < 64; o <<= 1) {
        int t = __shfl_up(x, o, 64);
        if (lane >= o) x += t;
    }
    if (lane < nb) bsum[lane] = x - orig;
}

__global__ void scan_apply(const unsigned* __restrict__ cnt, const int* __restrict__ bsum,
                           int* __restrict__ off, int* __restrict__ offw,
                           float* __restrict__ cntf, int n) {
    int base = blockIdx.x * 1024 + threadIdx.x * 4;
    int add = bsum[blockIdx.x];
#pragma unroll
    for (int i = 0; i < 4; ++i) {
        int idx = base + i;
        if (idx < n) {
            int o = off[idx] + add;
            off[idx] = o;
            offw[idx] = o;
            cntf[idx] = (float)cnt[idx];
        }
    }
}

__global__ void place_kernel(const int* __restrict__ edge, int* __restrict__ offw,
                             int* __restrict__ sortedB, int E) {
    int stride = gridDim.x * blockDim.x;
    for (int e = blockIdx.x * blockDim.x + threadIdx.x; e < E; e += stride) {
        int a = edge[e];
        int pos = atomicAdd(&offw[a], 1);
        sortedB[pos] = edge[E + e];
    }
}

// ---------------------------------------------------------------------------
// Weight prep: wt[c][k] = bf16(w[k][c])
// ---------------------------------------------------------------------------
__global__ void prep_wt(const float* __restrict__ w, short* __restrict__ wt, int K, int OC) {
    int id = blockIdx.x * blockDim.x + threadIdx.x;
    if (id < K * OC) {
        int k = id / OC, c = id % OC;
        wt[(size_t)c * K + k] = f2bf(w[id]);
    }
}

__global__ void concat_bias(const float* __restrict__ bq, const float* __restrict__ bk,
                            const float* __restrict__ bv, float* __restrict__ bqkv) {
    int t = threadIdx.x;
    bqkv[t] = bq[t];
    bqkv[128 + t] = bk[t];
    bqkv[256 + t] = bv[t];
}

// ---------------------------------------------------------------------------
// MFMA GEMM: block = 16 rows x OC cols; one wave per 64-col strip (BLK = OC).
// All waves read the SAME 16-row A tile -> 1 HBM fetch + L2 broadcast.
// Optional fused: input scale/shift (BN), GELU, residual (+BN'd), bf16 out,
// and per-column batchnorm stats (sum/sumsq) striped into 64 atomic slots.
// Frag maps (v_mfma_f32_16x16x32_bf16): A/B: m|n=lane&15, k=(lane>>4)*8+e;
// C/D: col=lane&15, row=(lane>>4)*4+reg.
// ---------------------------------------------------------------------------
template<int BLK, int KT, bool IN_BF16, bool INSCALE, bool GELU, bool OUT_BF16, bool RESID, bool RSCALED, bool STATS>
__global__ __launch_bounds__(BLK) void mfma_gemm(
    const void* __restrict__ Xv, const short* __restrict__ Wt, const float* __restrict__ bias,
    const float* __restrict__ in_sc, const float* __restrict__ in_sh,
    const float* __restrict__ resid, const float* __restrict__ r_sc, const float* __restrict__ r_sh,
    void* __restrict__ outv, float* __restrict__ slots, int n, int OC)
{
    const int lane = threadIdx.x & 63;
    const int wm = threadIdx.x >> 6;        // wave = column strip
    const int R0 = blockIdx.x * 16;
    const int C0 = wm * 64;
    const int l15 = lane & 15;
    const int kg = lane >> 4;
    const int rowA = min(R0 + l15, n - 1);

    const float* Xf = (const float*)Xv;
    const short* Xb = (const short*)Xv;

    f4 acc[4];
#pragma unroll
    for (int cf = 0; cf < 4; ++cf) acc[cf] = 0.f;

    constexpr int NCH = KT / 128;
#pragma unroll
    for (int kc = 0; kc < NCH; ++kc) {
        bh8 B[4][4];
#pragma unroll
        for (int cf = 0; cf < 4; ++cf) {
            int col = C0 + cf * 16 + l15;
#pragma unroll
            for (int ks = 0; ks < 4; ++ks)
                B[cf][ks] = *(const bh8*)(Wt + (size_t)col * KT + kc * 128 + ks * 32 + kg * 8);
        }
#pragma unroll
        for (int ks = 0; ks < 4; ++ks) {
            int kbase = kc * 128 + ks * 32 + kg * 8;
            bh8 a;
            if constexpr (IN_BF16) {
                a = *(const bh8*)(Xb + (size_t)rowA * KT + kbase);
            } else {
                f4 lo = *(const f4*)(Xf + (size_t)rowA * KT + kbase);
                f4 hi = *(const f4*)(Xf + (size_t)rowA * KT + kbase + 4);
                if constexpr (INSCALE) {
                    f4 sl = *(const f4*)(in_sc + kbase);
                    f4 sh_ = *(const f4*)(in_sc + kbase + 4);
                    f4 tl = *(const f4*)(in_sh + kbase);
                    f4 th = *(const f4*)(in_sh + kbase + 4);
                    lo = lo * sl + tl;
                    hi = hi * sh_ + th;
                }
                a[0] = f2bf(lo[0]); a[1] = f2bf(lo[1]); a[2] = f2bf(lo[2]); a[3] = f2bf(lo[3]);
                a[4] = f2bf(hi[0]); a[5] = f2bf(hi[1]); a[6] = f2bf(hi[2]); a[7] = f2bf(hi[3]);
            }
#pragma unroll
            for (int cf = 0; cf < 4; ++cf)
                acc[cf] = __builtin_amdgcn_mfma_f32_16x16x32_bf16(a, B[cf][ks], acc[cf], 0, 0, 0);
        }
    }

    // epilogue
#pragma unroll
    for (int cf = 0; cf < 4; ++cf) {
        int col = C0 + cf * 16 + l15;
        float b = bias[col];
        float rs = 0.f, rh = 0.f;
        if constexpr (RSCALED) { rs = r_sc[col]; rh = r_sh[col]; }
        float s = 0.f, q = 0.f;
#pragma unroll
        for (int i = 0; i < 4; ++i) {
            int row = R0 + kg * 4 + i;
            if (row < n) {
                float val = acc[cf][i] + b;
                if constexpr (RESID) {
                    float rv = resid[(size_t)row * EMB + col];
                    if constexpr (RSCALED) rv = rv * rs + rh;
                    val += rv;
                }
                if constexpr (GELU) val = 0.5f * val * (1.0f + erff(val * 0.70710678f));
                if constexpr (STATS) { s += val; q += val * val; }
                if constexpr (OUT_BF16) ((short*)outv)[(size_t)row * OC + col] = f2bf(val);
                else                    ((float*)outv)[(size_t)row * OC + col] = val;
            }
        }
        if constexpr (STATS) {
            // reduce over kg (block's 16 rows): lanes l15, l15+16, l15+32, l15+48
            s += __shfl_xor(s, 16, 64); s += __shfl_xor(s, 32, 64);
            q += __shfl_xor(q, 16, 64); q += __shfl_xor(q, 32, 64);
            if (kg == 0) {
                float* sl = slots + (size_t)(blockIdx.x & 63) * 256;
                unsafeAtomicAdd(&sl[col], s);
                unsafeAtomicAdd(&sl[128 + col], q);
            }
        }
    }
}

// ---------------------------------------------------------------------------
// Gather: ksum[n,:] = sum over sorted neighbor list of k rows (bf16 in qkv).
// ---------------------------------------------------------------------------
__global__ void gather_kernel(const short* __restrict__ qkv, const int* __restrict__ off,
                              const unsigned* __restrict__ cnt, const int* __restrict__ sortedB,
                              short* __restrict__ ksum, int n) {
    int wid = (int)((blockIdx.x * blockDim.x + threadIdx.x) >> 6);
    int lane = threadIdx.x & 63;
    int nw = (gridDim.x * blockDim.x) >> 6;
    for (int node = wid; node < n; node += nw) {
        int start = off[node];
        int deg = (int)cnt[node];
        float a0 = 0.f, a1 = 0.f;
        int j = 0;
        for (; j + 4 <= deg; j += 4) {
            int b0 = sortedB[start + j + 0];
            int b1 = sortedB[start + j + 1];
            int b2 = sortedB[start + j + 2];
            int b3 = sortedB[start + j + 3];
            unsigned u0 = *(const unsigned*)(qkv + (size_t)b0 * 384 + 128 + 2 * lane);
            unsigned u1 = *(const unsigned*)(qkv + (size_t)b1 * 384 + 128 + 2 * lane);
            unsigned u2 = *(const unsigned*)(qkv + (size_t)b2 * 384 + 128 + 2 * lane);
            unsigned u3 = *(const unsigned*)(qkv + (size_t)b3 * 384 + 128 + 2 * lane);
            a0 += (bfbits2f(u0 & 0xffffu) + bfbits2f(u1 & 0xffffu)) + (bfbits2f(u2 & 0xffffu) + bfbits2f(u3 & 0xffffu));
            a1 += (bfbits2f(u0 >> 16) + bfbits2f(u1 >> 16)) + (bfbits2f(u2 >> 16) + bfbits2f(u3 >> 16));
        }
        for (; j < deg; ++j) {
            int b = sortedB[start + j];
            unsigned u = *(const unsigned*)(qkv + (size_t)b * 384 + 128 + 2 * lane);
            a0 += bfbits2f(u & 0xffffu);
            a1 += bfbits2f(u >> 16);
        }
        unsigned pk = (unsigned)(unsigned short)f2bf(a0) | ((unsigned)(unsigned short)f2bf(a1) << 16);
        *(unsigned*)(ksum + (size_t)node * EMB + 2 * lane) = pk;
    }
}

// ---------------------------------------------------------------------------
// Attention: one wave per node. lane = (h,g) in 8x8. All bf16 in, bf16 out.
// ---------------------------------------------------------------------------
__global__ void attn_kernel(const short* __restrict__ qkv, const short* __restrict__ ksum,
                            const float* __restrict__ cnt, short* __restrict__ attno, int n) {
    int wavesPerBlock = blockDim.x >> 6;
    int wid = blockIdx.x * wavesPerBlock + (threadIdx.x >> 6);
    int lane = threadIdx.x & 63;
    int totalWaves = gridDim.x * wavesPerBlock;
    int h = lane >> 3, g = lane & 7;
    for (int node = wid; node < n; node += totalWaves) {
        const short* qp = qkv + (size_t)node * 384 + h * 16;
        const short* kp = ksum + (size_t)node * EMB + g * 16;
        uint4 qa = *(const uint4*)qp;
        uint4 qb = *(const uint4*)(qp + 8);
        uint4 ka = *(const uint4*)kp;
        uint4 kb = *(const uint4*)(kp + 8);
        float s = bdot2(qa.x, ka.x) + bdot2(qa.y, ka.y) + bdot2(qa.z, ka.z) + bdot2(qa.w, ka.w)
                + bdot2(qb.x, kb.x) + bdot2(qb.y, kb.y) + bdot2(qb.z, kb.z) + bdot2(qb.w, kb.w);
        float c = cnt[node];
        s *= 1.0f / fmaxf(c, 1.0f);
        float m = s;
#pragma unroll
        for (int off = 1; off < 8; off <<= 1) m = fmaxf(m, __shfl_xor(m, off, 64));
        float e = __expf(s - m);
        float sum = e;
#pragma unroll
        for (int off = 1; off < 8; off <<= 1) sum += __shfl_xor(sum, off, 64);
        float p = e / sum;
        float o0 = 0.f, o1 = 0.f;
        int d0 = g * 2;
#pragma unroll
        for (int gg = 0; gg < 8; ++gg) {
            float pg = __shfl(p, h * 8 + gg, 64);
            unsigned vv = *(const unsigned*)(qkv + (size_t)node * 384 + 256 + gg * 16 + d0);
            o0 += pg * bfbits2f(vv & 0xffffu);
            o1 += pg * bfbits2f(vv >> 16);
        }
        unsigned pk = (unsigned)(unsigned short)f2bf(o0) | ((unsigned)(unsigned short)f2bf(o1) << 16);
        *(unsigned*)(attno + (size_t)node * EMB + h * 16 + d0) = pk;
    }
}

// ---------------------------------------------------------------------------
// BatchNorm: reduce 64 stat slots -> scale/shift
// ---------------------------------------------------------------------------
__global__ void bn_finalize_slots(const float* __restrict__ slots, float* __restrict__ scsh,
                                  const float* __restrict__ g, const float* __restrict__ be, int n) {
    int c = threadIdx.x;
    float s = 0.f, q = 0.f;
    for (int i = 0; i < 64; ++i) {
        s += slots[(size_t)i * 256 + c];
        q += slots[(size_t)i * 256 + 128 + c];
    }
    float invn = 1.0f / (float)n;
    float mean = s * invn;
    float var = fmaxf(q * invn - mean * mean, 0.f);
    float sc = g[c] * rsqrtf(var + 1e-5f);
    scsh[c] = sc;
    scsh[128 + c] = be[c] - mean * sc;
}

__global__ void bn_apply(float* __restrict__ Y, const float* __restrict__ scsh, size_t total4) {
    size_t stride = (size_t)gridDim.x * blockDim.x;
    for (size_t i = (size_t)blockIdx.x * blockDim.x + threadIdx.x; i < total4; i += stride) {
        f4 vv = ((f4*)Y)[i];
        int c = (int)((i * 4) & 127);
#pragma unroll
        for (int j = 0; j < 4; ++j) vv[j] = vv[j] * scsh[c + j] + scsh[128 + c + j];
        ((f4*)Y)[i] = vv;
    }
}

// ---------------------------------------------------------------------------
extern "C" void kernel_launch(void* const* d_in, const int* in_sizes, int n_in,
                              void* d_out, int out_size, void* d_ws, size_t ws_size,
                              hipStream_t stream) {
    const float* x   = (const float*)d_in[0];
    const float* wq  = (const float*)d_in[1];
    const float* bq  = (const float*)d_in[2];
    const float* wk  = (const float*)d_in[3];
    const float* bk  = (const float*)d_in[4];
    const float* wv  = (const float*)d_in[5];
    const float* bv  = (const float*)d_in[6];
    const float* wo  = (const float*)d_in[7];
    const float* bo  = (const float*)d_in[8];
    const float* w1  = (const float*)d_in[9];
    const float* b1  = (const float*)d_in[10];
    const float* w2  = (const float*)d_in[11];
    const float* b2  = (const float*)d_in[12];
    const float* g1  = (const float*)d_in[13];
    const float* be1 = (const float*)d_in[14];
    const float* g2  = (const float*)d_in[15];
    const float* be2 = (const float*)d_in[16];
    const int* edge  = (const int*)d_in[17];

    int n = in_sizes[0] / EMB;      // 50000
    int E = in_sizes[17] / 2;       // 800000

    // workspace layout (float units)
    float* wsf = (float*)d_ws;
    unsigned* cnt_u = (unsigned*)wsf;                       // 65536
    float*  cntf  = wsf + 65536;                            // 65536
    int*    off   = (int*)(wsf + 2 * 65536);                // 65536
    int*    offw  = (int*)(wsf + 3 * 65536);                // 65536
    int*    bsum  = (int*)(wsf + 4 * 65536);                // 64
    int*    sortedB = (int*)(wsf + 4 * 65536 + 64);         // E
    float*  base5 = wsf + 4 * 65536 + 64 + E;
    short*  qkv   = (short*)base5;                          // n*384 bf16 = n*192 f
    short*  ksum  = (short*)(base5 + (size_t)n * 192);      // n*128 bf16 = n*64 f
    short*  attno = (short*)(base5 + (size_t)n * 256);      // n*128 bf16 = n*64 f
    float*  y1    = base5 + (size_t)n * 320;                // n*128 f
    float*  warea = y1 + (size_t)n * 128;
    short*  wqkvT = (short*)warea;                          // 384*128 bf16 = 24576 f
    short*  woT   = wqkvT + 384 * 128;                      // 128*128
    short*  w1T   = woT + 128 * 128;                        // 512*128
    short*  w2T   = w1T + 512 * 128;                        // 128*512
    float*  bqkv  = (float*)(w2T + 128 * 512);              // 384
    float*  slots1 = bqkv + 384;                            // 64*256
    float*  slots2 = slots1 + 64 * 256;                     // 64*256
    float*  scsh1  = slots2 + 64 * 256;                     // 256
    float*  scsh2  = scsh1 + 256;                           // 256
    short*  hbuf  = qkv;                                    // n*512 bf16 (spans qkv+ksum, both dead)
    float*  y2    = (float*)d_out;

    hipMemsetAsync(cnt_u, 0, 65536 * sizeof(unsigned), stream);
    hipMemsetAsync(slots1, 0, 2 * 64 * 256 * sizeof(float), stream);

    // edge counting sort
    int nb = (n + 1023) / 1024;  // 49
    hist_kernel<<<2048, 256, 0, stream>>>(edge, cnt_u, E);
    scan_blocks<<<nb, 256, 0, stream>>>(cnt_u, off, bsum, n);
    scan_bsums<<<1, 64, 0, stream>>>(bsum, nb);
    scan_apply<<<nb, 256, 0, stream>>>(cnt_u, bsum, off, offw, cntf, n);
    place_kernel<<<2048, 256, 0, stream>>>(edge, offw, sortedB, E);

    // weight prep
    prep_wt<<<(128 * 128 + 255) / 256, 256, 0, stream>>>(wq, wqkvT, 128, 128);
    prep_wt<<<(128 * 128 + 255) / 256, 256, 0, stream>>>(wk, wqkvT + 128 * 128, 128, 128);
    prep_wt<<<(128 * 128 + 255) / 256, 256, 0, stream>>>(wv, wqkvT + 256 * 128, 128, 128);
    prep_wt<<<(128 * 128 + 255) / 256, 256, 0, stream>>>(wo, woT, 128, 128);
    prep_wt<<<(128 * 512 + 255) / 256, 256, 0, stream>>>(w1, w1T, 128, 512);
    prep_wt<<<(512 * 128 + 255) / 256, 256, 0, stream>>>(w2, w2T, 512, 128);
    concat_bias<<<1, 128, 0, stream>>>(bq, bk, bv, bqkv);

    int gr16 = (n + 15) / 16;  // 3125

    // qkv = x @ [wq|wk|wv] + bqkv  (fp32 in, converted in-reg; bf16 out [n][384])
    mfma_gemm<384, 128, false, false, false, true, false, false, false><<<gr16, 384, 0, stream>>>(
        x, wqkvT, bqkv, nullptr, nullptr, nullptr, nullptr, nullptr, qkv, nullptr, n, 384);

    // ksum[n] = sum of k rows of neighbors (cnt*bk included automatically)
    gather_kernel<<<2048, 256, 0, stream>>>(qkv, off, cnt_u, sortedB, ksum, n);

    attn_kernel<<<512, 256, 0, stream>>>(qkv, ksum, cntf, attno, n);

    // y1 = attno@wo + bo + x (fp32 out) + fused BN1 stats
    mfma_gemm<128, 128, true, false, false, false, true, false, true><<<gr16, 128, 0, stream>>>(
        attno, woT, bo, nullptr, nullptr, x, nullptr, nullptr, y1, slots1, n, EMB);

    bn_finalize_slots<<<1, 128, 0, stream>>>(slots1, scsh1, g1, be1, n);

    // h = gelu(bn1(y1)@w1 + b1), bf16 out
    mfma_gemm<512, 128, false, true, true, true, false, false, false><<<gr16, 512, 0, stream>>>(
        y1, w1T, b1, scsh1, scsh1 + 128, nullptr, nullptr, nullptr, hbuf, nullptr, n, HID);

    // y2 = h@w2 + b2 + bn1(y1) (fp32 out to d_out) + fused BN2 stats
    mfma_gemm<128, 512, true, false, false, false, true, true, true><<<gr16, 128, 0, stream>>>(
        hbuf, w2T, b2, nullptr, nullptr, y1, scsh1, scsh1 + 128, y2, slots2, n, EMB);

    bn_finalize_slots<<<1, 128, 0, stream>>>(slots2, scsh2, g2, be2, n);
    bn_apply<<<512, 256, 0, stream>>>(y2, scsh2, (size_t)n * EMB / 4);
}

// Round 7
// 420.732 us; speedup vs baseline: 2.1845x; 1.0607x over previous
//
#include <hip/hip_runtime.h>
#include <hip/hip_bf16.h>

typedef float f4 __attribute__((ext_vector_type(4)));
typedef short bh8 __attribute__((ext_vector_type(8)));   // 8 bf16 (4 VGPRs)

#define EMB 128
#define HID 512

__device__ __forceinline__ float bfbits2f(unsigned int lo16) {
    unsigned int u = lo16 << 16;
    return __builtin_bit_cast(float, u);
}
__device__ __forceinline__ short f2bf(float f) {
    __hip_bfloat16 h = __float2bfloat16(f);
    return __builtin_bit_cast(short, h);
}
__device__ __forceinline__ float bdot2(unsigned a, unsigned b) {
    return bfbits2f(a & 0xffffu) * bfbits2f(b & 0xffffu) + bfbits2f(a >> 16) * bfbits2f(b >> 16);
}

// ---------------------------------------------------------------------------
// Counting sort of edges by destination A.
// ---------------------------------------------------------------------------
__global__ void hist_kernel(const int* __restrict__ edge, unsigned* __restrict__ cnt, int E) {
    int stride = gridDim.x * blockDim.x;
    for (int e = blockIdx.x * blockDim.x + threadIdx.x; e < E; e += stride)
        atomicAdd(&cnt[edge[e]], 1u);
}

// Hierarchical exclusive scan: 256 threads x 4 elements per block.
__global__ void scan_blocks(const unsigned* __restrict__ cnt, int* __restrict__ off,
                            int* __restrict__ bsum, int n) {
    __shared__ int ls[256];
    int tid = threadIdx.x;
    int base = blockIdx.x * 1024 + tid * 4;
    int v0 = 0, v1 = 0, v2 = 0, v3 = 0;
    if (base + 0 < n) v0 = (int)cnt[base + 0];
    if (base + 1 < n) v1 = (int)cnt[base + 1];
    if (base + 2 < n) v2 = (int)cnt[base + 2];
    if (base + 3 < n) v3 = (int)cnt[base + 3];
    int s = v0 + v1 + v2 + v3;
    ls[tid] = s;
    __syncthreads();
    for (int d = 1; d < 256; d <<= 1) {
        int t = (tid >= d) ? ls[tid - d] : 0;
        __syncthreads();
        ls[tid] += t;
        __syncthreads();
    }
    int incl = ls[tid];
    int run = incl - s;
    if (tid == 255) bsum[blockIdx.x] = incl;
    if (base + 0 < n) { off[base + 0] = run; run += v0; }
    if (base + 1 < n) { off[base + 1] = run; run += v1; }
    if (base + 2 < n) { off[base + 2] = run; run += v2; }
    if (base + 3 < n) { off[base + 3] = run; }
}

__global__ void scan_bsums(int* __restrict__ bsum, int nb) {
    int lane = threadIdx.x & 63;
    int x = (lane < nb) ? bsum[lane] : 0;
    int orig = x;
#pragma unroll
    for (int o = 1; o < 64; o <<= 1) {
        int t = __shfl_up(x, o, 64);
        if (lane >= o) x += t;
    }
    if (lane < nb) bsum[lane] = x - orig;
}

__global__ void scan_apply(const unsigned* __restrict__ cnt, const int* __restrict__ bsum,
                           int* __restrict__ off, int* __restrict__ offw,
                           float* __restrict__ cntf, int n) {
    int base = blockIdx.x * 1024 + threadIdx.x * 4;
    int add = bsum[blockIdx.x];
#pragma unroll
    for (int i = 0; i < 4; ++i) {
        int idx = base + i;
        if (idx < n) {
            int o = off[idx] + add;
            off[idx] = o;
            offw[idx] = o;
            cntf[idx] = (float)cnt[idx];
        }
    }
}

__global__ void place_kernel(const int* __restrict__ edge, int* __restrict__ offw,
                             int* __restrict__ sortedB, int E) {
    int stride = gridDim.x * blockDim.x;
    for (int e = blockIdx.x * blockDim.x + threadIdx.x; e < E; e += stride) {
        int a = edge[e];
        int pos = atomicAdd(&offw[a], 1);
        sortedB[pos] = edge[E + e];
    }
}

// ---------------------------------------------------------------------------
// Weight prep: wt[c][k] = bf16(w[k][c])
// ---------------------------------------------------------------------------
__global__ void prep_wt(const float* __restrict__ w, short* __restrict__ wt, int K, int OC) {
    int id = blockIdx.x * blockDim.x + threadIdx.x;
    if (id < K * OC) {
        int k = id / OC, c = id % OC;
        wt[(size_t)c * K + k] = f2bf(w[id]);
    }
}

__global__ void concat_bias(const float* __restrict__ bq, const float* __restrict__ bk,
                            const float* __restrict__ bv, float* __restrict__ bqkv) {
    int t = threadIdx.x;
    bqkv[t] = bq[t];
    bqkv[128 + t] = bk[t];
    bqkv[256 + t] = bv[t];
}

// ---------------------------------------------------------------------------
// MFMA GEMM: block = 256 threads = 2x2 waves; 128 rows x 128 cols per block,
// 64x64 per wave (4x4 fragments, 16 f4 accumulators). Grid: (n/128, OC/128).
// A re-read across column blocks is absorbed by L2/L3; B panel read once per
// 128-row block. Optional fused: input scale/shift (BN), GELU, residual
// (+BN'd), bf16 out, per-column BN stats into 64 atomic slot groups.
// Frag maps (v_mfma_f32_16x16x32_bf16): A/B: m|n=lane&15, k=(lane>>4)*8+e;
// C/D: col=lane&15, row=(lane>>4)*4+reg.
// ---------------------------------------------------------------------------
template<int KT, bool IN_BF16, bool INSCALE, bool GELU, bool OUT_BF16, bool RESID, bool RSCALED, bool STATS>
__global__ __launch_bounds__(256) void mfma_gemm(
    const void* __restrict__ Xv, const short* __restrict__ Wt, const float* __restrict__ bias,
    const float* __restrict__ in_sc, const float* __restrict__ in_sh,
    const float* __restrict__ resid, const float* __restrict__ r_sc, const float* __restrict__ r_sh,
    void* __restrict__ outv, float* __restrict__ slots, int n, int OC)
{
    const int lane = threadIdx.x & 63;
    const int w = threadIdx.x >> 6;
    const int wr = w >> 1, wc = w & 1;
    const int R0 = blockIdx.x * 128 + wr * 64;
    const int C0 = blockIdx.y * 128 + wc * 64;
    const int l15 = lane & 15;
    const int kg = lane >> 4;

    const float* Xf = (const float*)Xv;
    const short* Xb = (const short*)Xv;

    int rowA[4];
#pragma unroll
    for (int rf = 0; rf < 4; ++rf) rowA[rf] = min(R0 + rf * 16 + l15, n - 1);

    f4 acc[4][4];
#pragma unroll
    for (int rf = 0; rf < 4; ++rf)
#pragma unroll
        for (int cf = 0; cf < 4; ++cf) acc[rf][cf] = 0.f;

    constexpr int NCH = KT / 128;
#pragma unroll
    for (int kc = 0; kc < NCH; ++kc) {
#pragma unroll
        for (int ks = 0; ks < 4; ++ks) {
            const int kbase = kc * 128 + ks * 32 + kg * 8;
            bh8 a[4], b[4];
#pragma unroll
            for (int rf = 0; rf < 4; ++rf) {
                if constexpr (IN_BF16) {
                    a[rf] = *(const bh8*)(Xb + (size_t)rowA[rf] * KT + kbase);
                } else {
                    f4 lo = *(const f4*)(Xf + (size_t)rowA[rf] * KT + kbase);
                    f4 hi = *(const f4*)(Xf + (size_t)rowA[rf] * KT + kbase + 4);
                    if constexpr (INSCALE) {
                        f4 sl = *(const f4*)(in_sc + kbase);
                        f4 sh_ = *(const f4*)(in_sc + kbase + 4);
                        f4 tl = *(const f4*)(in_sh + kbase);
                        f4 th = *(const f4*)(in_sh + kbase + 4);
                        lo = lo * sl + tl;
                        hi = hi * sh_ + th;
                    }
                    bh8 t;
                    t[0] = f2bf(lo[0]); t[1] = f2bf(lo[1]); t[2] = f2bf(lo[2]); t[3] = f2bf(lo[3]);
                    t[4] = f2bf(hi[0]); t[5] = f2bf(hi[1]); t[6] = f2bf(hi[2]); t[7] = f2bf(hi[3]);
                    a[rf] = t;
                }
            }
#pragma unroll
            for (int cf = 0; cf < 4; ++cf)
                b[cf] = *(const bh8*)(Wt + (size_t)(C0 + cf * 16 + l15) * KT + kbase);
#pragma unroll
            for (int rf = 0; rf < 4; ++rf)
#pragma unroll
                for (int cf = 0; cf < 4; ++cf)
                    acc[rf][cf] = __builtin_amdgcn_mfma_f32_16x16x32_bf16(a[rf], b[cf], acc[rf][cf], 0, 0, 0);
        }
    }

    // epilogue
#pragma unroll
    for (int cf = 0; cf < 4; ++cf) {
        const int col = C0 + cf * 16 + l15;
        const float bcol = bias[col];
        float rs = 0.f, rh = 0.f;
        if constexpr (RSCALED) { rs = r_sc[col]; rh = r_sh[col]; }
#pragma unroll
        for (int rf = 0; rf < 4; ++rf) {
            float s = 0.f, q = 0.f;
#pragma unroll
            for (int i = 0; i < 4; ++i) {
                const int row = R0 + rf * 16 + kg * 4 + i;
                if (row < n) {
                    float val = acc[rf][cf][i] + bcol;
                    if constexpr (RESID) {
                        float rv = resid[(size_t)row * EMB + col];
                        if constexpr (RSCALED) rv = rv * rs + rh;
                        val += rv;
                    }
                    if constexpr (GELU) val = 0.5f * val * (1.0f + erff(val * 0.70710678f));
                    if constexpr (STATS) { s += val; q += val * val; }
                    if constexpr (OUT_BF16) ((short*)outv)[(size_t)row * OC + col] = f2bf(val);
                    else                    ((float*)outv)[(size_t)row * OC + col] = val;
                }
            }
            if constexpr (STATS) {
                s += __shfl_xor(s, 16, 64); s += __shfl_xor(s, 32, 64);
                q += __shfl_xor(q, 16, 64); q += __shfl_xor(q, 32, 64);
                if (kg == 0) {
                    float* sl = slots + (size_t)(blockIdx.x & 63) * 256;
                    unsafeAtomicAdd(&sl[col], s);
                    unsafeAtomicAdd(&sl[128 + col], q);
                }
            }
        }
    }
}

// ---------------------------------------------------------------------------
// Gather: ksum[n,:] = sum over sorted neighbor list of k rows (bf16 in qkv).
// ---------------------------------------------------------------------------
__global__ void gather_kernel(const short* __restrict__ qkv, const int* __restrict__ off,
                              const unsigned* __restrict__ cnt, const int* __restrict__ sortedB,
                              short* __restrict__ ksum, int n) {
    int wid = (int)((blockIdx.x * blockDim.x + threadIdx.x) >> 6);
    int lane = threadIdx.x & 63;
    int nw = (gridDim.x * blockDim.x) >> 6;
    for (int node = wid; node < n; node += nw) {
        int start = off[node];
        int deg = (int)cnt[node];
        float a0 = 0.f, a1 = 0.f;
        int j = 0;
        for (; j + 4 <= deg; j += 4) {
            int b0 = sortedB[start + j + 0];
            int b1 = sortedB[start + j + 1];
            int b2 = sortedB[start + j + 2];
            int b3 = sortedB[start + j + 3];
            unsigned u0 = *(const unsigned*)(qkv + (size_t)b0 * 384 + 128 + 2 * lane);
            unsigned u1 = *(const unsigned*)(qkv + (size_t)b1 * 384 + 128 + 2 * lane);
            unsigned u2 = *(const unsigned*)(qkv + (size_t)b2 * 384 + 128 + 2 * lane);
            unsigned u3 = *(const unsigned*)(qkv + (size_t)b3 * 384 + 128 + 2 * lane);
            a0 += (bfbits2f(u0 & 0xffffu) + bfbits2f(u1 & 0xffffu)) + (bfbits2f(u2 & 0xffffu) + bfbits2f(u3 & 0xffffu));
            a1 += (bfbits2f(u0 >> 16) + bfbits2f(u1 >> 16)) + (bfbits2f(u2 >> 16) + bfbits2f(u3 >> 16));
        }
        for (; j < deg; ++j) {
            int b = sortedB[start + j];
            unsigned u = *(const unsigned*)(qkv + (size_t)b * 384 + 128 + 2 * lane);
            a0 += bfbits2f(u & 0xffffu);
            a1 += bfbits2f(u >> 16);
        }
        unsigned pk = (unsigned)(unsigned short)f2bf(a0) | ((unsigned)(unsigned short)f2bf(a1) << 16);
        *(unsigned*)(ksum + (size_t)node * EMB + 2 * lane) = pk;
    }
}

// ---------------------------------------------------------------------------
// Attention: one wave per node. lane = (h,g) in 8x8. All bf16 in, bf16 out.
// ---------------------------------------------------------------------------
__global__ void attn_kernel(const short* __restrict__ qkv, const short* __restrict__ ksum,
                            const float* __restrict__ cnt, short* __restrict__ attno, int n) {
    int wavesPerBlock = blockDim.x >> 6;
    int wid = blockIdx.x * wavesPerBlock + (threadIdx.x >> 6);
    int lane = threadIdx.x & 63;
    int totalWaves = gridDim.x * wavesPerBlock;
    int h = lane >> 3, g = lane & 7;
    for (int node = wid; node < n; node += totalWaves) {
        const short* qp = qkv + (size_t)node * 384 + h * 16;
        const short* kp = ksum + (size_t)node * EMB + g * 16;
        uint4 qa = *(const uint4*)qp;
        uint4 qb = *(const uint4*)(qp + 8);
        uint4 ka = *(const uint4*)kp;
        uint4 kb = *(const uint4*)(kp + 8);
        float s = bdot2(qa.x, ka.x) + bdot2(qa.y, ka.y) + bdot2(qa.z, ka.z) + bdot2(qa.w, ka.w)
                + bdot2(qb.x, kb.x) + bdot2(qb.y, kb.y) + bdot2(qb.z, kb.z) + bdot2(qb.w, kb.w);
        float c = cnt[node];
        s *= 1.0f / fmaxf(c, 1.0f);
        float m = s;
#pragma unroll
        for (int off = 1; off < 8; off <<= 1) m = fmaxf(m, __shfl_xor(m, off, 64));
        float e = __expf(s - m);
        float sum = e;
#pragma unroll
        for (int off = 1; off < 8; off <<= 1) sum += __shfl_xor(sum, off, 64);
        float p = e / sum;
        float o0 = 0.f, o1 = 0.f;
        int d0 = g * 2;
#pragma unroll
        for (int gg = 0; gg < 8; ++gg) {
            float pg = __shfl(p, h * 8 + gg, 64);
            unsigned vv = *(const unsigned*)(qkv + (size_t)node * 384 + 256 + gg * 16 + d0);
            o0 += pg * bfbits2f(vv & 0xffffu);
            o1 += pg * bfbits2f(vv >> 16);
        }
        unsigned pk = (unsigned)(unsigned short)f2bf(o0) | ((unsigned)(unsigned short)f2bf(o1) << 16);
        *(unsigned*)(attno + (size_t)node * EMB + h * 16 + d0) = pk;
    }
}

// ---------------------------------------------------------------------------
// BatchNorm: reduce 64 stat slots -> scale/shift
// ---------------------------------------------------------------------------
__global__ void bn_finalize_slots(const float* __restrict__ slots, float* __restrict__ scsh,
                                  const float* __restrict__ g, const float* __restrict__ be, int n) {
    int c = threadIdx.x;
    float s = 0.f, q = 0.f;
    for (int i = 0; i < 64; ++i) {
        s += slots[(size_t)i * 256 + c];
        q += slots[(size_t)i * 256 + 128 + c];
    }
    float invn = 1.0f / (float)n;
    float mean = s * invn;
    float var = fmaxf(q * invn - mean * mean, 0.f);
    float sc = g[c] * rsqrtf(var + 1e-5f);
    scsh[c] = sc;
    scsh[128 + c] = be[c] - mean * sc;
}

__global__ void bn_apply(float* __restrict__ Y, const float* __restrict__ scsh, size_t total4) {
    size_t stride = (size_t)gridDim.x * blockDim.x;
    for (size_t i = (size_t)blockIdx.x * blockDim.x + threadIdx.x; i < total4; i += stride) {
        f4 vv = ((f4*)Y)[i];
        int c = (int)((i * 4) & 127);
#pragma unroll
        for (int j = 0; j < 4; ++j) vv[j] = vv[j] * scsh[c + j] + scsh[128 + c + j];
        ((f4*)Y)[i] = vv;
    }
}

// ---------------------------------------------------------------------------
extern "C" void kernel_launch(void* const* d_in, const int* in_sizes, int n_in,
                              void* d_out, int out_size, void* d_ws, size_t ws_size,
                              hipStream_t stream) {
    const float* x   = (const float*)d_in[0];
    const float* wq  = (const float*)d_in[1];
    const float* bq  = (const float*)d_in[2];
    const float* wk  = (const float*)d_in[3];
    const float* bk  = (const float*)d_in[4];
    const float* wv  = (const float*)d_in[5];
    const float* bv  = (const float*)d_in[6];
    const float* wo  = (const float*)d_in[7];
    const float* bo  = (const float*)d_in[8];
    const float* w1  = (const float*)d_in[9];
    const float* b1  = (const float*)d_in[10];
    const float* w2  = (const float*)d_in[11];
    const float* b2  = (const float*)d_in[12];
    const float* g1  = (const float*)d_in[13];
    const float* be1 = (const float*)d_in[14];
    const float* g2  = (const float*)d_in[15];
    const float* be2 = (const float*)d_in[16];
    const int* edge  = (const int*)d_in[17];

    int n = in_sizes[0] / EMB;      // 50000
    int E = in_sizes[17] / 2;       // 800000

    // workspace layout (float units)
    float* wsf = (float*)d_ws;
    unsigned* cnt_u = (unsigned*)wsf;                       // 65536
    float*  cntf  = wsf + 65536;                            // 65536
    int*    off   = (int*)(wsf + 2 * 65536);                // 65536
    int*    offw  = (int*)(wsf + 3 * 65536);                // 65536
    int*    bsum  = (int*)(wsf + 4 * 65536);                // 64
    int*    sortedB = (int*)(wsf + 4 * 65536 + 64);         // E
    float*  base5 = wsf + 4 * 65536 + 64 + E;
    short*  qkv   = (short*)base5;                          // n*384 bf16 = n*192 f
    short*  ksum  = (short*)(base5 + (size_t)n * 192);      // n*128 bf16 = n*64 f
    short*  attno = (short*)(base5 + (size_t)n * 256);      // n*128 bf16 = n*64 f
    float*  y1    = base5 + (size_t)n * 320;                // n*128 f
    float*  warea = y1 + (size_t)n * 128;
    short*  wqkvT = (short*)warea;                          // 384*128 bf16 = 24576 f
    short*  woT   = wqkvT + 384 * 128;                      // 128*128
    short*  w1T   = woT + 128 * 128;                        // 512*128
    short*  w2T   = w1T + 512 * 128;                        // 128*512
    float*  bqkv  = (float*)(w2T + 128 * 512);              // 384
    float*  slots1 = bqkv + 384;                            // 64*256
    float*  slots2 = slots1 + 64 * 256;                     // 64*256
    float*  scsh1  = slots2 + 64 * 256;                     // 256
    float*  scsh2  = scsh1 + 256;                           // 256
    short*  hbuf  = qkv;                                    // n*512 bf16 (spans qkv+ksum, both dead)
    float*  y2    = (float*)d_out;

    hipMemsetAsync(cnt_u, 0, 65536 * sizeof(unsigned), stream);
    hipMemsetAsync(slots1, 0, 2 * 64 * 256 * sizeof(float), stream);

    // edge counting sort
    int nb = (n + 1023) / 1024;  // 49
    hist_kernel<<<2048, 256, 0, stream>>>(edge, cnt_u, E);
    scan_blocks<<<nb, 256, 0, stream>>>(cnt_u, off, bsum, n);
    scan_bsums<<<1, 64, 0, stream>>>(bsum, nb);
    scan_apply<<<nb, 256, 0, stream>>>(cnt_u, bsum, off, offw, cntf, n);
    place_kernel<<<2048, 256, 0, stream>>>(edge, offw, sortedB, E);

    // weight prep
    prep_wt<<<(128 * 128 + 255) / 256, 256, 0, stream>>>(wq, wqkvT, 128, 128);
    prep_wt<<<(128 * 128 + 255) / 256, 256, 0, stream>>>(wk, wqkvT + 128 * 128, 128, 128);
    prep_wt<<<(128 * 128 + 255) / 256, 256, 0, stream>>>(wv, wqkvT + 256 * 128, 128, 128);
    prep_wt<<<(128 * 128 + 255) / 256, 256, 0, stream>>>(wo, woT, 128, 128);
    prep_wt<<<(128 * 512 + 255) / 256, 256, 0, stream>>>(w1, w1T, 128, 512);
    prep_wt<<<(512 * 128 + 255) / 256, 256, 0, stream>>>(w2, w2T, 512, 128);
    concat_bias<<<1, 128, 0, stream>>>(bq, bk, bv, bqkv);

    int gr128 = (n + 127) / 128;  // 391

    // qkv = x @ [wq|wk|wv] + bqkv  (fp32 in, converted in-reg; bf16 out [n][384])
    mfma_gemm<128, false, false, false, true, false, false, false><<<dim3(gr128, 3), 256, 0, stream>>>(
        x, wqkvT, bqkv, nullptr, nullptr, nullptr, nullptr, nullptr, qkv, nullptr, n, 384);

    // ksum[n] = sum of k rows of neighbors (cnt*bk included automatically)
    gather_kernel<<<2048, 256, 0, stream>>>(qkv, off, cnt_u, sortedB, ksum, n);

    attn_kernel<<<512, 256, 0, stream>>>(qkv, ksum, cntf, attno, n);

    // y1 = attno@wo + bo + x (fp32 out) + fused BN1 stats
    mfma_gemm<128, true, false, false, false, true, false, true><<<dim3(gr128, 1), 256, 0, stream>>>(
        attno, woT, bo, nullptr, nullptr, x, nullptr, nullptr, y1, slots1, n, EMB);

    bn_finalize_slots<<<1, 128, 0, stream>>>(slots1, scsh1, g1, be1, n);

    // h = gelu(bn1(y1)@w1 + b1), bf16 out
    mfma_gemm<128, false, true, true, true, false, false, false><<<dim3(gr128, 4), 256, 0, stream>>>(
        y1, w1T, b1, scsh1, scsh1 + 128, nullptr, nullptr, nullptr, hbuf, nullptr, n, HID);

    // y2 = h@w2 + b2 + bn1(y1) (fp32 out to d_out) + fused BN2 stats
    mfma_gemm<512, true, false, false, false, true, true, true><<<dim3(gr128, 1), 256, 0, stream>>>(
        hbuf, w2T, b2, nullptr, nullptr, y1, scsh1, scsh1 + 128, y2, slots2, n, EMB);

    bn_finalize_slots<<<1, 128, 0, stream>>>(slots2, scsh2, g2, be2, n);
    bn_apply<<<512, 256, 0, stream>>>(y2, scsh2, (size_t)n * EMB / 4);
}

// Round 8
// 389.480 us; speedup vs baseline: 2.3598x; 1.0802x over previous
//
#include <hip/hip_runtime.h>
#include <hip/hip_bf16.h>

typedef float f4 __attribute__((ext_vector_type(4)));
typedef short bh8 __attribute__((ext_vector_type(8)));   // 8 bf16 (4 VGPRs)

#define EMB 128
#define HID 512

__device__ __forceinline__ float bfbits2f(unsigned int lo16) {
    unsigned int u = lo16 << 16;
    return __builtin_bit_cast(float, u);
}
__device__ __forceinline__ short f2bf(float f) {
    __hip_bfloat16 h = __float2bfloat16(f);
    return __builtin_bit_cast(short, h);
}
__device__ __forceinline__ float bdot2(unsigned a, unsigned b) {
    return bfbits2f(a & 0xffffu) * bfbits2f(b & 0xffffu) + bfbits2f(a >> 16) * bfbits2f(b >> 16);
}

// ---------------------------------------------------------------------------
// Counting sort of edges by destination A.
// ---------------------------------------------------------------------------
__global__ void hist_kernel(const int* __restrict__ edge, unsigned* __restrict__ cnt, int E) {
    int stride = gridDim.x * blockDim.x;
    for (int e = blockIdx.x * blockDim.x + threadIdx.x; e < E; e += stride)
        atomicAdd(&cnt[edge[e]], 1u);
}

// Hierarchical exclusive scan: 256 threads x 4 elements per block.
__global__ void scan_blocks(const unsigned* __restrict__ cnt, int* __restrict__ off,
                            int* __restrict__ bsum, int n) {
    __shared__ int ls[256];
    int tid = threadIdx.x;
    int base = blockIdx.x * 1024 + tid * 4;
    int v0 = 0, v1 = 0, v2 = 0, v3 = 0;
    if (base + 0 < n) v0 = (int)cnt[base + 0];
    if (base + 1 < n) v1 = (int)cnt[base + 1];
    if (base + 2 < n) v2 = (int)cnt[base + 2];
    if (base + 3 < n) v3 = (int)cnt[base + 3];
    int s = v0 + v1 + v2 + v3;
    ls[tid] = s;
    __syncthreads();
    for (int d = 1; d < 256; d <<= 1) {
        int t = (tid >= d) ? ls[tid - d] : 0;
        __syncthreads();
        ls[tid] += t;
        __syncthreads();
    }
    int incl = ls[tid];
    int run = incl - s;
    if (tid == 255) bsum[blockIdx.x] = incl;
    if (base + 0 < n) { off[base + 0] = run; run += v0; }
    if (base + 1 < n) { off[base + 1] = run; run += v1; }
    if (base + 2 < n) { off[base + 2] = run; run += v2; }
    if (base + 3 < n) { off[base + 3] = run; }
}

__global__ void scan_bsums(int* __restrict__ bsum, int nb) {
    int lane = threadIdx.x & 63;
    int x = (lane < nb) ? bsum[lane] : 0;
    int orig = x;
#pragma unroll
    for (int o = 1; o < 64; o <<= 1) {
        int t = __shfl_up(x, o, 64);
        if (lane >= o) x += t;
    }
    if (lane < nb) bsum[lane] = x - orig;
}

__global__ void scan_apply(const unsigned* __restrict__ cnt, const int* __restrict__ bsum,
                           int* __restrict__ off, int* __restrict__ offw,
                           float* __restrict__ cntf, int n) {
    int base = blockIdx.x * 1024 + threadIdx.x * 4;
    int add = bsum[blockIdx.x];
#pragma unroll
    for (int i = 0; i < 4; ++i) {
        int idx = base + i;
        if (idx < n) {
            int o = off[idx] + add;
            off[idx] = o;
            offw[idx] = o;
            cntf[idx] = (float)cnt[idx];
        }
    }
}

__global__ void place_kernel(const int* __restrict__ edge, int* __restrict__ offw,
                             int* __restrict__ sortedB, int E) {
    int stride = gridDim.x * blockDim.x;
    for (int e = blockIdx.x * blockDim.x + threadIdx.x; e < E; e += stride) {
        int a = edge[e];
        int pos = atomicAdd(&offw[a], 1);
        sortedB[pos] = edge[E + e];
    }
}

// ---------------------------------------------------------------------------
// Weight prep: wt[c][k] = bf16(w[k][c])
// ---------------------------------------------------------------------------
__global__ void prep_wt(const float* __restrict__ w, short* __restrict__ wt, int K, int OC) {
    int id = blockIdx.x * blockDim.x + threadIdx.x;
    if (id < K * OC) {
        int k = id / OC, c = id % OC;
        wt[(size_t)c * K + k] = f2bf(w[id]);
    }
}

__global__ void concat_bias(const float* __restrict__ bq, const float* __restrict__ bk,
                            const float* __restrict__ bv, float* __restrict__ bqkv) {
    int t = threadIdx.x;
    bqkv[t] = bq[t];
    bqkv[128 + t] = bk[t];
    bqkv[256 + t] = bv[t];
}

// ---------------------------------------------------------------------------
// MFMA GEMM: 256 threads = 2x2 waves; 128 rows x 128 cols per block, 64x64
// per wave. 1-D grid interleaved column-major: bx = blockIdx.x / ncolb,
// by = blockIdx.x % ncolb, so panels sharing A-rows dispatch together (A is
// HBM-fetched once, L2/L3 for the rest). bf16 output staged through padded
// LDS tile -> full-line dwordx4 stores (avoids 2-byte partial-line RMW).
// Frag maps (v_mfma_f32_16x16x32_bf16): A/B: m|n=lane&15, k=(lane>>4)*8+e;
// C/D: col=lane&15, row=(lane>>4)*4+reg.
// ---------------------------------------------------------------------------
#define CSTRIDE 136   // shorts; 272B row stride: 16B-aligned, breaks kg bank aliasing

template<int KT, bool IN_BF16, bool INSCALE, bool GELU, bool OUT_BF16, bool RESID, bool RSCALED, bool STATS>
__global__ __launch_bounds__(256) void mfma_gemm(
    const void* __restrict__ Xv, const short* __restrict__ Wt, const float* __restrict__ bias,
    const float* __restrict__ in_sc, const float* __restrict__ in_sh,
    const float* __restrict__ resid, const float* __restrict__ r_sc, const float* __restrict__ r_sh,
    void* __restrict__ outv, float* __restrict__ slots, int n, int OC, int ncolb)
{
    const int bx = blockIdx.x / ncolb;
    const int by = blockIdx.x % ncolb;
    const int lane = threadIdx.x & 63;
    const int w = threadIdx.x >> 6;
    const int wr = w >> 1, wc = w & 1;
    const int R0 = bx * 128 + wr * 64;
    const int C0 = by * 128 + wc * 64;
    const int l15 = lane & 15;
    const int kg = lane >> 4;

    const float* Xf = (const float*)Xv;
    const short* Xb = (const short*)Xv;

    int rowA[4];
#pragma unroll
    for (int rf = 0; rf < 4; ++rf) rowA[rf] = min(R0 + rf * 16 + l15, n - 1);

    f4 acc[4][4];
#pragma unroll
    for (int rf = 0; rf < 4; ++rf)
#pragma unroll
        for (int cf = 0; cf < 4; ++cf) acc[rf][cf] = 0.f;

    constexpr int NCH = KT / 128;
#pragma unroll
    for (int kc = 0; kc < NCH; ++kc) {
#pragma unroll
        for (int ks = 0; ks < 4; ++ks) {
            const int kbase = kc * 128 + ks * 32 + kg * 8;
            bh8 a[4], b[4];
#pragma unroll
            for (int rf = 0; rf < 4; ++rf) {
                if constexpr (IN_BF16) {
                    a[rf] = *(const bh8*)(Xb + (size_t)rowA[rf] * KT + kbase);
                } else {
                    f4 lo = *(const f4*)(Xf + (size_t)rowA[rf] * KT + kbase);
                    f4 hi = *(const f4*)(Xf + (size_t)rowA[rf] * KT + kbase + 4);
                    if constexpr (INSCALE) {
                        f4 sl = *(const f4*)(in_sc + kbase);
                        f4 sh_ = *(const f4*)(in_sc + kbase + 4);
                        f4 tl = *(const f4*)(in_sh + kbase);
                        f4 th = *(const f4*)(in_sh + kbase + 4);
                        lo = lo * sl + tl;
                        hi = hi * sh_ + th;
                    }
                    bh8 t;
                    t[0] = f2bf(lo[0]); t[1] = f2bf(lo[1]); t[2] = f2bf(lo[2]); t[3] = f2bf(lo[3]);
                    t[4] = f2bf(hi[0]); t[5] = f2bf(hi[1]); t[6] = f2bf(hi[2]); t[7] = f2bf(hi[3]);
                    a[rf] = t;
                }
            }
#pragma unroll
            for (int cf = 0; cf < 4; ++cf)
                b[cf] = *(const bh8*)(Wt + (size_t)(C0 + cf * 16 + l15) * KT + kbase);
#pragma unroll
            for (int rf = 0; rf < 4; ++rf)
#pragma unroll
                for (int cf = 0; cf < 4; ++cf)
                    acc[rf][cf] = __builtin_amdgcn_mfma_f32_16x16x32_bf16(a[rf], b[cf], acc[rf][cf], 0, 0, 0);
        }
    }

    if constexpr (OUT_BF16) {
        // epilogue -> LDS bf16 tile -> coalesced dwordx4 stores
        extern __shared__ short cs[];
        const int lrb = wr * 64;
        const int lcb = wc * 64;
#pragma unroll
        for (int cf = 0; cf < 4; ++cf) {
            const float bcol = bias[C0 + cf * 16 + l15];
#pragma unroll
            for (int rf = 0; rf < 4; ++rf) {
#pragma unroll
                for (int i = 0; i < 4; ++i) {
                    float val = acc[rf][cf][i] + bcol;
                    if constexpr (GELU) val = 0.5f * val * (1.0f + erff(val * 0.70710678f));
                    cs[(lrb + rf * 16 + kg * 4 + i) * CSTRIDE + lcb + cf * 16 + l15] = f2bf(val);
                }
            }
        }
        __syncthreads();
        const int tc = threadIdx.x & 15;
        const int tr = threadIdx.x >> 4;
        const int gcb = by * 128;
#pragma unroll
        for (int r = 0; r < 8; ++r) {
            int lrow = tr + r * 16;
            int grow = bx * 128 + lrow;
            if (grow < n) {
                bh8 v = *(bh8*)(cs + lrow * CSTRIDE + tc * 8);
                *(bh8*)((short*)outv + (size_t)grow * OC + gcb + tc * 8) = v;
            }
        }
    } else {
        // fp32 epilogue (+ optional residual, BN stats)
#pragma unroll
        for (int cf = 0; cf < 4; ++cf) {
            const int col = C0 + cf * 16 + l15;
            const float bcol = bias[col];
            float rs = 0.f, rh = 0.f;
            if constexpr (RSCALED) { rs = r_sc[col]; rh = r_sh[col]; }
#pragma unroll
            for (int rf = 0; rf < 4; ++rf) {
                float s = 0.f, q = 0.f;
#pragma unroll
                for (int i = 0; i < 4; ++i) {
                    const int row = R0 + rf * 16 + kg * 4 + i;
                    if (row < n) {
                        float val = acc[rf][cf][i] + bcol;
                        if constexpr (RESID) {
                            float rv = resid[(size_t)row * EMB + col];
                            if constexpr (RSCALED) rv = rv * rs + rh;
                            val += rv;
                        }
                        if constexpr (GELU) val = 0.5f * val * (1.0f + erff(val * 0.70710678f));
                        if constexpr (STATS) { s += val; q += val * val; }
                        ((float*)outv)[(size_t)row * OC + col] = val;
                    }
                }
                if constexpr (STATS) {
                    s += __shfl_xor(s, 16, 64); s += __shfl_xor(s, 32, 64);
                    q += __shfl_xor(q, 16, 64); q += __shfl_xor(q, 32, 64);
                    if (kg == 0) {
                        float* sl = slots + (size_t)(bx & 63) * 256;
                        unsafeAtomicAdd(&sl[col], s);
                        unsafeAtomicAdd(&sl[128 + col], q);
                    }
                }
            }
        }
    }
}

// ---------------------------------------------------------------------------
// Gather: ksum[n,:] = sum over sorted neighbor list of k rows (bf16 in qkv).
// ---------------------------------------------------------------------------
__global__ void gather_kernel(const short* __restrict__ qkv, const int* __restrict__ off,
                              const unsigned* __restrict__ cnt, const int* __restrict__ sortedB,
                              short* __restrict__ ksum, int n) {
    int wid = (int)((blockIdx.x * blockDim.x + threadIdx.x) >> 6);
    int lane = threadIdx.x & 63;
    int nw = (gridDim.x * blockDim.x) >> 6;
    for (int node = wid; node < n; node += nw) {
        int start = off[node];
        int deg = (int)cnt[node];
        float a0 = 0.f, a1 = 0.f;
        int j = 0;
        for (; j + 4 <= deg; j += 4) {
            int b0 = sortedB[start + j + 0];
            int b1 = sortedB[start + j + 1];
            int b2 = sortedB[start + j + 2];
            int b3 = sortedB[start + j + 3];
            unsigned u0 = *(const unsigned*)(qkv + (size_t)b0 * 384 + 128 + 2 * lane);
            unsigned u1 = *(const unsigned*)(qkv + (size_t)b1 * 384 + 128 + 2 * lane);
            unsigned u2 = *(const unsigned*)(qkv + (size_t)b2 * 384 + 128 + 2 * lane);
            unsigned u3 = *(const unsigned*)(qkv + (size_t)b3 * 384 + 128 + 2 * lane);
            a0 += (bfbits2f(u0 & 0xffffu) + bfbits2f(u1 & 0xffffu)) + (bfbits2f(u2 & 0xffffu) + bfbits2f(u3 & 0xffffu));
            a1 += (bfbits2f(u0 >> 16) + bfbits2f(u1 >> 16)) + (bfbits2f(u2 >> 16) + bfbits2f(u3 >> 16));
        }
        for (; j < deg; ++j) {
            int b = sortedB[start + j];
            unsigned u = *(const unsigned*)(qkv + (size_t)b * 384 + 128 + 2 * lane);
            a0 += bfbits2f(u & 0xffffu);
            a1 += bfbits2f(u >> 16);
        }
        unsigned pk = (unsigned)(unsigned short)f2bf(a0) | ((unsigned)(unsigned short)f2bf(a1) << 16);
        *(unsigned*)(ksum + (size_t)node * EMB + 2 * lane) = pk;
    }
}

// ---------------------------------------------------------------------------
// Attention: one wave per node. lane = (h,g) in 8x8. All bf16 in, bf16 out.
// ---------------------------------------------------------------------------
__global__ void attn_kernel(const short* __restrict__ qkv, const short* __restrict__ ksum,
                            const float* __restrict__ cnt, short* __restrict__ attno, int n) {
    int wavesPerBlock = blockDim.x >> 6;
    int wid = blockIdx.x * wavesPerBlock + (threadIdx.x >> 6);
    int lane = threadIdx.x & 63;
    int totalWaves = gridDim.x * wavesPerBlock;
    int h = lane >> 3, g = lane & 7;
    for (int node = wid; node < n; node += totalWaves) {
        const short* qp = qkv + (size_t)node * 384 + h * 16;
        const short* kp = ksum + (size_t)node * EMB + g * 16;
        uint4 qa = *(const uint4*)qp;
        uint4 qb = *(const uint4*)(qp + 8);
        uint4 ka = *(const uint4*)kp;
        uint4 kb = *(const uint4*)(kp + 8);
        float s = bdot2(qa.x, ka.x) + bdot2(qa.y, ka.y) + bdot2(qa.z, ka.z) + bdot2(qa.w, ka.w)
                + bdot2(qb.x, kb.x) + bdot2(qb.y, kb.y) + bdot2(qb.z, kb.z) + bdot2(qb.w, kb.w);
        float c = cnt[node];
        s *= 1.0f / fmaxf(c, 1.0f);
        float m = s;
#pragma unroll
        for (int off = 1; off < 8; off <<= 1) m = fmaxf(m, __shfl_xor(m, off, 64));
        float e = __expf(s - m);
        float sum = e;
#pragma unroll
        for (int off = 1; off < 8; off <<= 1) sum += __shfl_xor(sum, off, 64);
        float p = e / sum;
        float o0 = 0.f, o1 = 0.f;
        int d0 = g * 2;
#pragma unroll
        for (int gg = 0; gg < 8; ++gg) {
            float pg = __shfl(p, h * 8 + gg, 64);
            unsigned vv = *(const unsigned*)(qkv + (size_t)node * 384 + 256 + gg * 16 + d0);
            o0 += pg * bfbits2f(vv & 0xffffu);
            o1 += pg * bfbits2f(vv >> 16);
        }
        unsigned pk = (unsigned)(unsigned short)f2bf(o0) | ((unsigned)(unsigned short)f2bf(o1) << 16);
        *(unsigned*)(attno + (size_t)node * EMB + h * 16 + d0) = pk;
    }
}

// ---------------------------------------------------------------------------
// BatchNorm: reduce 64 stat slots -> scale/shift
// ---------------------------------------------------------------------------
__global__ void bn_finalize_slots(const float* __restrict__ slots, float* __restrict__ scsh,
                                  const float* __restrict__ g, const float* __restrict__ be, int n) {
    int c = threadIdx.x;
    float s = 0.f, q = 0.f;
    for (int i = 0; i < 64; ++i) {
        s += slots[(size_t)i * 256 + c];
        q += slots[(size_t)i * 256 + 128 + c];
    }
    float invn = 1.0f / (float)n;
    float mean = s * invn;
    float var = fmaxf(q * invn - mean * mean, 0.f);
    float sc = g[c] * rsqrtf(var + 1e-5f);
    scsh[c] = sc;
    scsh[128 + c] = be[c] - mean * sc;
}

__global__ void bn_apply(float* __restrict__ Y, const float* __restrict__ scsh, size_t total4) {
    size_t stride = (size_t)gridDim.x * blockDim.x;
    for (size_t i = (size_t)blockIdx.x * blockDim.x + threadIdx.x; i < total4; i += stride) {
        f4 vv = ((f4*)Y)[i];
        int c = (int)((i * 4) & 127);
#pragma unroll
        for (int j = 0; j < 4; ++j) vv[j] = vv[j] * scsh[c + j] + scsh[128 + c + j];
        ((f4*)Y)[i] = vv;
    }
}

// ---------------------------------------------------------------------------
extern "C" void kernel_launch(void* const* d_in, const int* in_sizes, int n_in,
                              void* d_out, int out_size, void* d_ws, size_t ws_size,
                              hipStream_t stream) {
    const float* x   = (const float*)d_in[0];
    const float* wq  = (const float*)d_in[1];
    const float* bq  = (const float*)d_in[2];
    const float* wk  = (const float*)d_in[3];
    const float* bk  = (const float*)d_in[4];
    const float* wv  = (const float*)d_in[5];
    const float* bv  = (const float*)d_in[6];
    const float* wo  = (const float*)d_in[7];
    const float* bo  = (const float*)d_in[8];
    const float* w1  = (const float*)d_in[9];
    const float* b1  = (const float*)d_in[10];
    const float* w2  = (const float*)d_in[11];
    const float* b2  = (const float*)d_in[12];
    const float* g1  = (const float*)d_in[13];
    const float* be1 = (const float*)d_in[14];
    const float* g2  = (const float*)d_in[15];
    const float* be2 = (const float*)d_in[16];
    const int* edge  = (const int*)d_in[17];

    int n = in_sizes[0] / EMB;      // 50000
    int E = in_sizes[17] / 2;       // 800000

    // workspace layout (float units)
    float* wsf = (float*)d_ws;
    unsigned* cnt_u = (unsigned*)wsf;                       // 65536
    float*  cntf  = wsf + 65536;                            // 65536
    int*    off   = (int*)(wsf + 2 * 65536);                // 65536
    int*    offw  = (int*)(wsf + 3 * 65536);                // 65536
    int*    bsum  = (int*)(wsf + 4 * 65536);                // 64
    int*    sortedB = (int*)(wsf + 4 * 65536 + 64);         // E
    float*  base5 = wsf + 4 * 65536 + 64 + E;
    short*  qkv   = (short*)base5;                          // n*384 bf16 = n*192 f
    short*  ksum  = (short*)(base5 + (size_t)n * 192);      // n*128 bf16 = n*64 f
    short*  attno = (short*)(base5 + (size_t)n * 256);      // n*128 bf16 = n*64 f
    float*  y1    = base5 + (size_t)n * 320;                // n*128 f
    float*  warea = y1 + (size_t)n * 128;
    short*  wqkvT = (short*)warea;                          // 384*128 bf16 = 24576 f
    short*  woT   = wqkvT + 384 * 128;                      // 128*128
    short*  w1T   = woT + 128 * 128;                        // 512*128
    short*  w2T   = w1T + 512 * 128;                        // 128*512
    float*  bqkv  = (float*)(w2T + 128 * 512);              // 384
    float*  slots1 = bqkv + 384;                            // 64*256
    float*  slots2 = slots1 + 64 * 256;                     // 64*256
    float*  scsh1  = slots2 + 64 * 256;                     // 256
    float*  scsh2  = scsh1 + 256;                           // 256
    short*  hbuf  = qkv;                                    // n*512 bf16 (spans qkv+ksum, both dead)
    float*  y2    = (float*)d_out;

    hipMemsetAsync(cnt_u, 0, 65536 * sizeof(unsigned), stream);
    hipMemsetAsync(slots1, 0, 2 * 64 * 256 * sizeof(float), stream);

    // edge counting sort
    int nb = (n + 1023) / 1024;  // 49
    hist_kernel<<<2048, 256, 0, stream>>>(edge, cnt_u, E);
    scan_blocks<<<nb, 256, 0, stream>>>(cnt_u, off, bsum, n);
    scan_bsums<<<1, 64, 0, stream>>>(bsum, nb);
    scan_apply<<<nb, 256, 0, stream>>>(cnt_u, bsum, off, offw, cntf, n);
    place_kernel<<<2048, 256, 0, stream>>>(edge, offw, sortedB, E);

    // weight prep
    prep_wt<<<(128 * 128 + 255) / 256, 256, 0, stream>>>(wq, wqkvT, 128, 128);
    prep_wt<<<(128 * 128 + 255) / 256, 256, 0, stream>>>(wk, wqkvT + 128 * 128, 128, 128);
    prep_wt<<<(128 * 128 + 255) / 256, 256, 0, stream>>>(wv, wqkvT + 256 * 128, 128, 128);
    prep_wt<<<(128 * 128 + 255) / 256, 256, 0, stream>>>(wo, woT, 128, 128);
    prep_wt<<<(128 * 512 + 255) / 256, 256, 0, stream>>>(w1, w1T, 128, 512);
    prep_wt<<<(512 * 128 + 255) / 256, 256, 0, stream>>>(w2, w2T, 512, 128);
    concat_bias<<<1, 128, 0, stream>>>(bq, bk, bv, bqkv);

    int gr128 = (n + 127) / 128;  // 391
    const size_t CSH = 128 * CSTRIDE * sizeof(short);  // 34816 B

    // qkv = x @ [wq|wk|wv] + bqkv  (fp32 in, converted in-reg; bf16 out [n][384])
    mfma_gemm<128, false, false, false, true, false, false, false><<<gr128 * 3, 256, CSH, stream>>>(
        x, wqkvT, bqkv, nullptr, nullptr, nullptr, nullptr, nullptr, qkv, nullptr, n, 384, 3);

    // ksum[n] = sum of k rows of neighbors (cnt*bk included automatically)
    gather_kernel<<<2048, 256, 0, stream>>>(qkv, off, cnt_u, sortedB, ksum, n);

    attn_kernel<<<512, 256, 0, stream>>>(qkv, ksum, cntf, attno, n);

    // y1 = attno@wo + bo + x (fp32 out) + fused BN1 stats
    mfma_gemm<128, true, false, false, false, true, false, true><<<gr128, 256, 0, stream>>>(
        attno, woT, bo, nullptr, nullptr, x, nullptr, nullptr, y1, slots1, n, EMB, 1);

    bn_finalize_slots<<<1, 128, 0, stream>>>(slots1, scsh1, g1, be1, n);

    // h = gelu(bn1(y1)@w1 + b1), bf16 out
    mfma_gemm<128, false, true, true, true, false, false, false><<<gr128 * 4, 256, CSH, stream>>>(
        y1, w1T, b1, scsh1, scsh1 + 128, nullptr, nullptr, nullptr, hbuf, nullptr, n, HID, 4);

    // y2 = h@w2 + b2 + bn1(y1) (fp32 out to d_out) + fused BN2 stats
    mfma_gemm<512, true, false, false, false, true, true, true><<<gr128, 256, 0, stream>>>(
        hbuf, w2T, b2, nullptr, nullptr, y1, scsh1, scsh1 + 128, y2, slots2, n, EMB, 1);

    bn_finalize_slots<<<1, 128, 0, stream>>>(slots2, scsh2, g2, be2, n);
    bn_apply<<<512, 256, 0, stream>>>(y2, scsh2, (size_t)n * EMB / 4);
}

// Round 9
// 372.278 us; speedup vs baseline: 2.4688x; 1.0462x over previous
//
#include <hip/hip_runtime.h>
#include <hip/hip_bf16.h>

typedef float f4 __attribute__((ext_vector_type(4)));
typedef short bh8 __attribute__((ext_vector_type(8)));   // 8 bf16 (4 VGPRs)

#define EMB 128
#define HID 512

__device__ __forceinline__ float bfbits2f(unsigned int lo16) {
    unsigned int u = lo16 << 16;
    return __builtin_bit_cast(float, u);
}
__device__ __forceinline__ short f2bf(float f) {
    __hip_bfloat16 h = __float2bfloat16(f);
    return __builtin_bit_cast(short, h);
}
__device__ __forceinline__ float bdot2(unsigned a, unsigned b) {
    return bfbits2f(a & 0xffffu) * bfbits2f(b & 0xffffu) + bfbits2f(a >> 16) * bfbits2f(b >> 16);
}

// ---------------------------------------------------------------------------
// Counting sort of edges by destination A.
// ---------------------------------------------------------------------------
__global__ void hist_kernel(const int* __restrict__ edge, unsigned* __restrict__ cnt, int E) {
    int stride = gridDim.x * blockDim.x;
    for (int e = blockIdx.x * blockDim.x + threadIdx.x; e < E; e += stride)
        atomicAdd(&cnt[edge[e]], 1u);
}

// Hierarchical exclusive scan: 256 threads x 4 elements per block.
__global__ void scan_blocks(const unsigned* __restrict__ cnt, int* __restrict__ off,
                            int* __restrict__ bsum, int n) {
    __shared__ int ls[256];
    int tid = threadIdx.x;
    int base = blockIdx.x * 1024 + tid * 4;
    int v0 = 0, v1 = 0, v2 = 0, v3 = 0;
    if (base + 0 < n) v0 = (int)cnt[base + 0];
    if (base + 1 < n) v1 = (int)cnt[base + 1];
    if (base + 2 < n) v2 = (int)cnt[base + 2];
    if (base + 3 < n) v3 = (int)cnt[base + 3];
    int s = v0 + v1 + v2 + v3;
    ls[tid] = s;
    __syncthreads();
    for (int d = 1; d < 256; d <<= 1) {
        int t = (tid >= d) ? ls[tid - d] : 0;
        __syncthreads();
        ls[tid] += t;
        __syncthreads();
    }
    int incl = ls[tid];
    int run = incl - s;
    if (tid == 255) bsum[blockIdx.x] = incl;
    if (base + 0 < n) { off[base + 0] = run; run += v0; }
    if (base + 1 < n) { off[base + 1] = run; run += v1; }
    if (base + 2 < n) { off[base + 2] = run; run += v2; }
    if (base + 3 < n) { off[base + 3] = run; }
}

__global__ void scan_bsums(int* __restrict__ bsum, int nb) {
    int lane = threadIdx.x & 63;
    int x = (lane < nb) ? bsum[lane] : 0;
    int orig = x;
#pragma unroll
    for (int o = 1; o < 64; o <<= 1) {
        int t = __shfl_up(x, o, 64);
        if (lane >= o) x += t;
    }
    if (lane < nb) bsum[lane] = x - orig;
}

__global__ void scan_apply(const unsigned* __restrict__ cnt, const int* __restrict__ bsum,
                           int* __restrict__ off, int* __restrict__ offw,
                           float* __restrict__ cntf, int n) {
    int base = blockIdx.x * 1024 + threadIdx.x * 4;
    int add = bsum[blockIdx.x];
#pragma unroll
    for (int i = 0; i < 4; ++i) {
        int idx = base + i;
        if (idx < n) {
            int o = off[idx] + add;
            off[idx] = o;
            offw[idx] = o;
            cntf[idx] = (float)cnt[idx];
        }
    }
}

__global__ void place_kernel(const int* __restrict__ edge, int* __restrict__ offw,
                             int* __restrict__ sortedB, int E) {
    int stride = gridDim.x * blockDim.x;
    for (int e = blockIdx.x * blockDim.x + threadIdx.x; e < E; e += stride) {
        int a = edge[e];
        int pos = atomicAdd(&offw[a], 1);
        sortedB[pos] = edge[E + e];
    }
}

// ---------------------------------------------------------------------------
// Weight prep: wt[c][k] = bf16(w[k][c])
// ---------------------------------------------------------------------------
__global__ void prep_wt(const float* __restrict__ w, short* __restrict__ wt, int K, int OC) {
    int id = blockIdx.x * blockDim.x + threadIdx.x;
    if (id < K * OC) {
        int k = id / OC, c = id % OC;
        wt[(size_t)c * K + k] = f2bf(w[id]);
    }
}

__global__ void concat_bias(const float* __restrict__ bq, const float* __restrict__ bk,
                            const float* __restrict__ bv, float* __restrict__ bqkv) {
    int t = threadIdx.x;
    bqkv[t] = bq[t];
    bqkv[128 + t] = bk[t];
    bqkv[256 + t] = bv[t];
}

// ---------------------------------------------------------------------------
// MFMA GEMM: 256 threads = 2x2 waves; 128 rows x 128 cols per block, 64x64
// per wave. 1-D grid interleaved column-major (bx = blockIdx.x / ncolb,
// by = blockIdx.x % ncolb) so panels sharing A-rows dispatch together.
// bf16 output staged through padded LDS tile -> full-line dwordx4 stores.
// RESID optionally reads bf16 residual (RBF16). STATS: fused per-column
// BN sum/sumsq into 64 atomic slot groups.
// Frag maps (v_mfma_f32_16x16x32_bf16): A/B: m|n=lane&15, k=(lane>>4)*8+e;
// C/D: col=lane&15, row=(lane>>4)*4+reg.
// ---------------------------------------------------------------------------
#define CSTRIDE 136   // shorts; 272B row stride: 16B-aligned, breaks kg bank aliasing

template<int KT, bool IN_BF16, bool GELU, bool OUT_BF16, bool RESID, bool RBF16, bool STATS>
__global__ __launch_bounds__(256) void mfma_gemm(
    const void* __restrict__ Xv, const short* __restrict__ Wt, const float* __restrict__ bias,
    const void* __restrict__ resid,
    void* __restrict__ outv, float* __restrict__ slots, int n, int OC, int ncolb)
{
    const int bx = blockIdx.x / ncolb;
    const int by = blockIdx.x % ncolb;
    const int lane = threadIdx.x & 63;
    const int w = threadIdx.x >> 6;
    const int wr = w >> 1, wc = w & 1;
    const int R0 = bx * 128 + wr * 64;
    const int C0 = by * 128 + wc * 64;
    const int l15 = lane & 15;
    const int kg = lane >> 4;

    const float* Xf = (const float*)Xv;
    const short* Xb = (const short*)Xv;

    int rowA[4];
#pragma unroll
    for (int rf = 0; rf < 4; ++rf) rowA[rf] = min(R0 + rf * 16 + l15, n - 1);

    f4 acc[4][4];
#pragma unroll
    for (int rf = 0; rf < 4; ++rf)
#pragma unroll
        for (int cf = 0; cf < 4; ++cf) acc[rf][cf] = 0.f;

    constexpr int NCH = KT / 128;
#pragma unroll
    for (int kc = 0; kc < NCH; ++kc) {
#pragma unroll
        for (int ks = 0; ks < 4; ++ks) {
            const int kbase = kc * 128 + ks * 32 + kg * 8;
            bh8 a[4], b[4];
#pragma unroll
            for (int rf = 0; rf < 4; ++rf) {
                if constexpr (IN_BF16) {
                    a[rf] = *(const bh8*)(Xb + (size_t)rowA[rf] * KT + kbase);
                } else {
                    f4 lo = *(const f4*)(Xf + (size_t)rowA[rf] * KT + kbase);
                    f4 hi = *(const f4*)(Xf + (size_t)rowA[rf] * KT + kbase + 4);
                    bh8 t;
                    t[0] = f2bf(lo[0]); t[1] = f2bf(lo[1]); t[2] = f2bf(lo[2]); t[3] = f2bf(lo[3]);
                    t[4] = f2bf(hi[0]); t[5] = f2bf(hi[1]); t[6] = f2bf(hi[2]); t[7] = f2bf(hi[3]);
                    a[rf] = t;
                }
            }
#pragma unroll
            for (int cf = 0; cf < 4; ++cf)
                b[cf] = *(const bh8*)(Wt + (size_t)(C0 + cf * 16 + l15) * KT + kbase);
#pragma unroll
            for (int rf = 0; rf < 4; ++rf)
#pragma unroll
                for (int cf = 0; cf < 4; ++cf)
                    acc[rf][cf] = __builtin_amdgcn_mfma_f32_16x16x32_bf16(a[rf], b[cf], acc[rf][cf], 0, 0, 0);
        }
    }

    if constexpr (OUT_BF16) {
        // epilogue -> LDS bf16 tile -> coalesced dwordx4 stores
        extern __shared__ short cs[];
        const int lrb = wr * 64;
        const int lcb = wc * 64;
#pragma unroll
        for (int cf = 0; cf < 4; ++cf) {
            const float bcol = bias[C0 + cf * 16 + l15];
#pragma unroll
            for (int rf = 0; rf < 4; ++rf) {
#pragma unroll
                for (int i = 0; i < 4; ++i) {
                    float val = acc[rf][cf][i] + bcol;
                    if constexpr (GELU) val = 0.5f * val * (1.0f + erff(val * 0.70710678f));
                    cs[(lrb + rf * 16 + kg * 4 + i) * CSTRIDE + lcb + cf * 16 + l15] = f2bf(val);
                }
            }
        }
        __syncthreads();
        const int tc = threadIdx.x & 15;
        const int tr = threadIdx.x >> 4;
        const int gcb = by * 128;
#pragma unroll
        for (int r = 0; r < 8; ++r) {
            int lrow = tr + r * 16;
            int grow = bx * 128 + lrow;
            if (grow < n) {
                bh8 v = *(bh8*)(cs + lrow * CSTRIDE + tc * 8);
                *(bh8*)((short*)outv + (size_t)grow * OC + gcb + tc * 8) = v;
            }
        }
    } else {
        // fp32 epilogue (+ optional residual fp32/bf16, BN stats)
#pragma unroll
        for (int cf = 0; cf < 4; ++cf) {
            const int col = C0 + cf * 16 + l15;
            const float bcol = bias[col];
#pragma unroll
            for (int rf = 0; rf < 4; ++rf) {
                float s = 0.f, q = 0.f;
#pragma unroll
                for (int i = 0; i < 4; ++i) {
                    const int row = R0 + rf * 16 + kg * 4 + i;
                    if (row < n) {
                        float val = acc[rf][cf][i] + bcol;
                        if constexpr (RESID) {
                            float rv;
                            if constexpr (RBF16)
                                rv = bfbits2f((unsigned short)((const short*)resid)[(size_t)row * EMB + col]);
                            else
                                rv = ((const float*)resid)[(size_t)row * EMB + col];
                            val += rv;
                        }
                        if constexpr (GELU) val = 0.5f * val * (1.0f + erff(val * 0.70710678f));
                        if constexpr (STATS) { s += val; q += val * val; }
                        ((float*)outv)[(size_t)row * OC + col] = val;
                    }
                }
                if constexpr (STATS) {
                    s += __shfl_xor(s, 16, 64); s += __shfl_xor(s, 32, 64);
                    q += __shfl_xor(q, 16, 64); q += __shfl_xor(q, 32, 64);
                    if (kg == 0) {
                        float* sl = slots + (size_t)(bx & 63) * 256;
                        unsafeAtomicAdd(&sl[col], s);
                        unsafeAtomicAdd(&sl[128 + col], q);
                    }
                }
            }
        }
    }
}

// ---------------------------------------------------------------------------
// Gather: ksum[n,:] = sum over sorted neighbor list of k rows (bf16 in qkv).
// ---------------------------------------------------------------------------
__global__ void gather_kernel(const short* __restrict__ qkv, const int* __restrict__ off,
                              const unsigned* __restrict__ cnt, const int* __restrict__ sortedB,
                              short* __restrict__ ksum, int n) {
    int wid = (int)((blockIdx.x * blockDim.x + threadIdx.x) >> 6);
    int lane = threadIdx.x & 63;
    int nw = (gridDim.x * blockDim.x) >> 6;
    for (int node = wid; node < n; node += nw) {
        int start = off[node];
        int deg = (int)cnt[node];
        float a0 = 0.f, a1 = 0.f;
        int j = 0;
        for (; j + 4 <= deg; j += 4) {
            int b0 = sortedB[start + j + 0];
            int b1 = sortedB[start + j + 1];
            int b2 = sortedB[start + j + 2];
            int b3 = sortedB[start + j + 3];
            unsigned u0 = *(const unsigned*)(qkv + (size_t)b0 * 384 + 128 + 2 * lane);
            unsigned u1 = *(const unsigned*)(qkv + (size_t)b1 * 384 + 128 + 2 * lane);
            unsigned u2 = *(const unsigned*)(qkv + (size_t)b2 * 384 + 128 + 2 * lane);
            unsigned u3 = *(const unsigned*)(qkv + (size_t)b3 * 384 + 128 + 2 * lane);
            a0 += (bfbits2f(u0 & 0xffffu) + bfbits2f(u1 & 0xffffu)) + (bfbits2f(u2 & 0xffffu) + bfbits2f(u3 & 0xffffu));
            a1 += (bfbits2f(u0 >> 16) + bfbits2f(u1 >> 16)) + (bfbits2f(u2 >> 16) + bfbits2f(u3 >> 16));
        }
        for (; j < deg; ++j) {
            int b = sortedB[start + j];
            unsigned u = *(const unsigned*)(qkv + (size_t)b * 384 + 128 + 2 * lane);
            a0 += bfbits2f(u & 0xffffu);
            a1 += bfbits2f(u >> 16);
        }
        unsigned pk = (unsigned)(unsigned short)f2bf(a0) | ((unsigned)(unsigned short)f2bf(a1) << 16);
        *(unsigned*)(ksum + (size_t)node * EMB + 2 * lane) = pk;
    }
}

// ---------------------------------------------------------------------------
// Attention: one wave per node. lane = (h,g) in 8x8. All bf16 in, bf16 out.
// ---------------------------------------------------------------------------
__global__ void attn_kernel(const short* __restrict__ qkv, const short* __restrict__ ksum,
                            const float* __restrict__ cnt, short* __restrict__ attno, int n) {
    int wavesPerBlock = blockDim.x >> 6;
    int wid = blockIdx.x * wavesPerBlock + (threadIdx.x >> 6);
    int lane = threadIdx.x & 63;
    int totalWaves = gridDim.x * wavesPerBlock;
    int h = lane >> 3, g = lane & 7;
    for (int node = wid; node < n; node += totalWaves) {
        const short* qp = qkv + (size_t)node * 384 + h * 16;
        const short* kp = ksum + (size_t)node * EMB + g * 16;
        uint4 qa = *(const uint4*)qp;
        uint4 qb = *(const uint4*)(qp + 8);
        uint4 ka = *(const uint4*)kp;
        uint4 kb = *(const uint4*)(kp + 8);
        float s = bdot2(qa.x, ka.x) + bdot2(qa.y, ka.y) + bdot2(qa.z, ka.z) + bdot2(qa.w, ka.w)
                + bdot2(qb.x, kb.x) + bdot2(qb.y, kb.y) + bdot2(qb.z, kb.z) + bdot2(qb.w, kb.w);
        float c = cnt[node];
        s *= 1.0f / fmaxf(c, 1.0f);
        float m = s;
#pragma unroll
        for (int off = 1; off < 8; off <<= 1) m = fmaxf(m, __shfl_xor(m, off, 64));
        float e = __expf(s - m);
        float sum = e;
#pragma unroll
        for (int off = 1; off < 8; off <<= 1) sum += __shfl_xor(sum, off, 64);
        float p = e / sum;
        float o0 = 0.f, o1 = 0.f;
        int d0 = g * 2;
#pragma unroll
        for (int gg = 0; gg < 8; ++gg) {
            float pg = __shfl(p, h * 8 + gg, 64);
            unsigned vv = *(const unsigned*)(qkv + (size_t)node * 384 + 256 + gg * 16 + d0);
            o0 += pg * bfbits2f(vv & 0xffffu);
            o1 += pg * bfbits2f(vv >> 16);
        }
        unsigned pk = (unsigned)(unsigned short)f2bf(o0) | ((unsigned)(unsigned short)f2bf(o1) << 16);
        *(unsigned*)(attno + (size_t)node * EMB + h * 16 + d0) = pk;
    }
}

// ---------------------------------------------------------------------------
// BatchNorm: reduce 64 stat slots -> scale/shift
// ---------------------------------------------------------------------------
__global__ void bn_finalize_slots(const float* __restrict__ slots, float* __restrict__ scsh,
                                  const float* __restrict__ g, const float* __restrict__ be, int n) {
    int c = threadIdx.x;
    float s = 0.f, q = 0.f;
    for (int i = 0; i < 64; ++i) {
        s += slots[(size_t)i * 256 + c];
        q += slots[(size_t)i * 256 + 128 + c];
    }
    float invn = 1.0f / (float)n;
    float mean = s * invn;
    float var = fmaxf(q * invn - mean * mean, 0.f);
    float sc = g[c] * rsqrtf(var + 1e-5f);
    scsh[c] = sc;
    scsh[128 + c] = be[c] - mean * sc;
}

// xn1 = bf16(bn1(y1)) : read fp32, apply scale/shift, write bf16
__global__ void apply_bn_bf16(const float* __restrict__ Y, const float* __restrict__ scsh,
                              short* __restrict__ out, size_t total8) {
    size_t stride = (size_t)gridDim.x * blockDim.x;
    for (size_t i = (size_t)blockIdx.x * blockDim.x + threadIdx.x; i < total8; i += stride) {
        size_t base = i * 8;
        f4 lo = *(const f4*)(Y + base);
        f4 hi = *(const f4*)(Y + base + 4);
        int c = (int)(base & 127);
        f4 s0 = *(const f4*)(scsh + c);
        f4 s1 = *(const f4*)(scsh + c + 4);
        f4 h0 = *(const f4*)(scsh + 128 + c);
        f4 h1 = *(const f4*)(scsh + 128 + c + 4);
        lo = lo * s0 + h0;
        hi = hi * s1 + h1;
        bh8 o;
        o[0] = f2bf(lo[0]); o[1] = f2bf(lo[1]); o[2] = f2bf(lo[2]); o[3] = f2bf(lo[3]);
        o[4] = f2bf(hi[0]); o[5] = f2bf(hi[1]); o[6] = f2bf(hi[2]); o[7] = f2bf(hi[3]);
        *(bh8*)(out + base) = o;
    }
}

__global__ void bn_apply(float* __restrict__ Y, const float* __restrict__ scsh, size_t total4) {
    size_t stride = (size_t)gridDim.x * blockDim.x;
    for (size_t i = (size_t)blockIdx.x * blockDim.x + threadIdx.x; i < total4; i += stride) {
        f4 vv = ((f4*)Y)[i];
        int c = (int)((i * 4) & 127);
#pragma unroll
        for (int j = 0; j < 4; ++j) vv[j] = vv[j] * scsh[c + j] + scsh[128 + c + j];
        ((f4*)Y)[i] = vv;
    }
}

// ---------------------------------------------------------------------------
extern "C" void kernel_launch(void* const* d_in, const int* in_sizes, int n_in,
                              void* d_out, int out_size, void* d_ws, size_t ws_size,
                              hipStream_t stream) {
    const float* x   = (const float*)d_in[0];
    const float* wq  = (const float*)d_in[1];
    const float* bq  = (const float*)d_in[2];
    const float* wk  = (const float*)d_in[3];
    const float* bk  = (const float*)d_in[4];
    const float* wv  = (const float*)d_in[5];
    const float* bv  = (const float*)d_in[6];
    const float* wo  = (const float*)d_in[7];
    const float* bo  = (const float*)d_in[8];
    const float* w1  = (const float*)d_in[9];
    const float* b1  = (const float*)d_in[10];
    const float* w2  = (const float*)d_in[11];
    const float* b2  = (const float*)d_in[12];
    const float* g1  = (const float*)d_in[13];
    const float* be1 = (const float*)d_in[14];
    const float* g2  = (const float*)d_in[15];
    const float* be2 = (const float*)d_in[16];
    const int* edge  = (const int*)d_in[17];

    int n = in_sizes[0] / EMB;      // 50000
    int E = in_sizes[17] / 2;       // 800000

    // workspace layout (float units)
    float* wsf = (float*)d_ws;
    unsigned* cnt_u = (unsigned*)wsf;                       // 65536
    float*  cntf  = wsf + 65536;                            // 65536
    int*    off   = (int*)(wsf + 2 * 65536);                // 65536
    int*    offw  = (int*)(wsf + 3 * 65536);                // 65536
    int*    bsum  = (int*)(wsf + 4 * 65536);                // 64
    int*    sortedB = (int*)(wsf + 4 * 65536 + 64);         // E
    float*  base5 = wsf + 4 * 65536 + 64 + E;
    short*  qkv   = (short*)base5;                          // n*384 bf16 = n*192 f
    short*  ksum  = (short*)(base5 + (size_t)n * 192);      // n*128 bf16 = n*64 f
    short*  attno = (short*)(base5 + (size_t)n * 256);      // n*128 bf16 = n*64 f
    float*  y1    = base5 + (size_t)n * 320;                // n*128 f
    float*  warea = y1 + (size_t)n * 128;
    short*  wqkvT = (short*)warea;                          // 384*128 bf16 = 24576 f
    short*  woT   = wqkvT + 384 * 128;                      // 128*128
    short*  w1T   = woT + 128 * 128;                        // 512*128
    short*  w2T   = w1T + 512 * 128;                        // 128*512
    float*  bqkv  = (float*)(w2T + 128 * 512);              // 384
    float*  slots1 = bqkv + 384;                            // 64*256
    float*  slots2 = slots1 + 64 * 256;                     // 64*256
    float*  scsh1  = slots2 + 64 * 256;                     // 256
    float*  scsh2  = scsh1 + 256;                           // 256
    short*  hbuf  = qkv;                                    // n*512 bf16 (spans qkv+ksum, both dead after attn)
    short*  xn1   = attno;                                  // n*128 bf16 (attno dead after wo-GEMM)
    float*  y2    = (float*)d_out;

    hipMemsetAsync(cnt_u, 0, 65536 * sizeof(unsigned), stream);
    hipMemsetAsync(slots1, 0, 2 * 64 * 256 * sizeof(float), stream);

    // edge counting sort
    int nb = (n + 1023) / 1024;  // 49
    hist_kernel<<<2048, 256, 0, stream>>>(edge, cnt_u, E);
    scan_blocks<<<nb, 256, 0, stream>>>(cnt_u, off, bsum, n);
    scan_bsums<<<1, 64, 0, stream>>>(bsum, nb);
    scan_apply<<<nb, 256, 0, stream>>>(cnt_u, bsum, off, offw, cntf, n);
    place_kernel<<<2048, 256, 0, stream>>>(edge, offw, sortedB, E);

    // weight prep
    prep_wt<<<(128 * 128 + 255) / 256, 256, 0, stream>>>(wq, wqkvT, 128, 128);
    prep_wt<<<(128 * 128 + 255) / 256, 256, 0, stream>>>(wk, wqkvT + 128 * 128, 128, 128);
    prep_wt<<<(128 * 128 + 255) / 256, 256, 0, stream>>>(wv, wqkvT + 256 * 128, 128, 128);
    prep_wt<<<(128 * 128 + 255) / 256, 256, 0, stream>>>(wo, woT, 128, 128);
    prep_wt<<<(128 * 512 + 255) / 256, 256, 0, stream>>>(w1, w1T, 128, 512);
    prep_wt<<<(512 * 128 + 255) / 256, 256, 0, stream>>>(w2, w2T, 512, 128);
    concat_bias<<<1, 128, 0, stream>>>(bq, bk, bv, bqkv);

    int gr128 = (n + 127) / 128;  // 391
    const size_t CSH = 128 * CSTRIDE * sizeof(short);  // 34816 B

    // qkv = x @ [wq|wk|wv] + bqkv  (fp32 in, converted in-reg; bf16 out [n][384])
    mfma_gemm<128, false, false, true, false, false, false><<<gr128 * 3, 256, CSH, stream>>>(
        x, wqkvT, bqkv, nullptr, qkv, nullptr, n, 384, 3);

    // ksum[n] = sum of k rows of neighbors (cnt*bk included automatically)
    gather_kernel<<<2048, 256, 0, stream>>>(qkv, off, cnt_u, sortedB, ksum, n);

    attn_kernel<<<512, 256, 0, stream>>>(qkv, ksum, cntf, attno, n);

    // y1 = attno@wo + bo + x (fp32 out) + fused BN1 stats
    mfma_gemm<128, true, false, false, true, false, true><<<gr128, 256, 0, stream>>>(
        attno, woT, bo, x, y1, slots1, n, EMB, 1);

    bn_finalize_slots<<<1, 128, 0, stream>>>(slots1, scsh1, g1, be1, n);

    // xn1 = bf16(bn1(y1))  (overwrites attno region; attno is dead)
    apply_bn_bf16<<<1600, 256, 0, stream>>>(y1, scsh1, xn1, (size_t)n * EMB / 8);

    // h = gelu(xn1@w1 + b1), bf16 out (pure bf16 A-stream, no per-load VALU)
    mfma_gemm<128, true, true, true, false, false, false><<<gr128 * 4, 256, CSH, stream>>>(
        xn1, w1T, b1, nullptr, hbuf, nullptr, n, HID, 4);

    // y2 = h@w2 + b2 + xn1 (bf16 resid; fp32 out to d_out) + fused BN2 stats
    mfma_gemm<512, true, false, false, true, true, true><<<gr128, 256, 0, stream>>>(
        hbuf, w2T, b2, xn1, y2, slots2, n, EMB, 1);

    bn_finalize_slots<<<1, 128, 0, stream>>>(slots2, scsh2, g2, be2, n);
    bn_apply<<<512, 256, 0, stream>>>(y2, scsh2, (size_t)n * EMB / 4);
}